// Round 10
// baseline (22088.637 us; speedup 1.0000x reference)
//
#include <hip/hip_runtime.h>
#include <stdint.h>
#include <stddef.h>

// Problem constants (from reference)
#define HIDN 256
#define GATES 1024
#define INL 512
#define BB 128
#define TT 1024
#define TSS 8
#define DIN 128
#define DOUT 8

typedef unsigned short u16;
typedef unsigned int u32;
typedef unsigned long long u64;
typedef __bf16 bf16x8_t __attribute__((ext_vector_type(8)));
typedef float f32x4_t __attribute__((ext_vector_type(4)));
typedef short s16x8_t __attribute__((ext_vector_type(8)));
typedef u16 u16x4_t __attribute__((ext_vector_type(4)));

union V8 { s16x8_t s; bf16x8_t b; };

__device__ __forceinline__ u16 f2bf(float f){
  unsigned u = __builtin_bit_cast(unsigned, f);
  u += 0x7FFFu + ((u >> 16) & 1u);
  return (u16)(u >> 16);
}
__device__ __forceinline__ float bf2f(u16 h){
  unsigned u = ((unsigned)h) << 16;
  return __builtin_bit_cast(float, u);
}
__device__ __forceinline__ float sigmoidf_(float x){ return 1.f/(1.f + __expf(-x)); }
__device__ __forceinline__ float tanhf_(float x){
  float ax = fabsf(x);
  float e = __expf(-2.f*ax);          // no overflow for any x
  float t = (1.f - e)/(1.f + e);
  return x < 0.f ? -t : t;
}

// ---------------------------------------------------------------- converts
__global__ __launch_bounds__(256) void cvt_f32_bf16(const float* __restrict__ in,
                                                    u16* __restrict__ out, int n4){
  int i = blockIdx.x*256 + threadIdx.x;
  if (i < n4){
    float4 f = ((const float4*)in)[i];
    u16x4_t u;
    u[0] = f2bf(f.x); u[1] = f2bf(f.y); u[2] = f2bf(f.z); u[3] = f2bf(f.w);
    ((u16x4_t*)out)[i] = u;
  }
}

// Pack Whh [1024][256] f32 into MFMA B-fragment order (bf16):
// frag (nt,kt): lane l, elem e -> Whh[nt*16 + (l&15)][kt*32 + (l>>4)*8 + e]
__global__ __launch_bounds__(256) void pack_whh(const float* __restrict__ Whh,
                                                u16* __restrict__ wf){
  int idx = blockIdx.x*256 + threadIdx.x;     // 32768 total
  int l  = idx & 63;
  int kt = (idx >> 6) & 7;
  int nt = idx >> 9;
  int j = nt*16 + (l & 15);
  int k = kt*32 + (l >> 4)*8;
  const float* src = Whh + (long)j*HIDN + k;
  s16x8_t pk;
  #pragma unroll
  for (int e=0;e<8;e++) pk[e] = (short)f2bf(src[e]);
  *(s16x8_t*)(wf + (long)idx*8) = pk;
}

// ---------------------------------------------------------------- GEMM
// C[M][N] = A[M][K] @ W[N][K]^T (+bias1+bias2), fp32 accum, bf16 out.
// global_load_lds width-16 staging, LINEAR LDS [128][32] (m97 structure).
// XA=0: A bf16, source row = (srcT0 + sdir*by)*128 + row (row stride K)
// XA=1: A = x f32 [B=128][T=1024][128]; source row = row*1024 + (srcT0+sdir*by)
// OM=0: plain rows C[(by*128+row)*N + col]
// OM=1: packed for lstm_rec9 (16-wave consumer):
//       dst = (((by*8+slice)*16 + w2)*1024) + (lg*16+lr)*16 + g*4 + r
template<int XA, int OM>
__global__ __launch_bounds__(256, 2) void gemm_tile(
    const void* __restrict__ Av, const u16* __restrict__ W,
    u16* __restrict__ C,
    const float* __restrict__ bias1, const float* __restrict__ bias2,
    int K, int N, int srcT0, int sdir)
{
  __shared__ u16 As[128*32];
  __shared__ u16 Ws[128*32];
  const int tid = threadIdx.x;
  const int l = tid & 63, wid = tid >> 6;
  const int lr = l & 15, lg = l >> 4;
  const int wm = (wid >> 1)*64, wn = (wid & 1)*64;
  const int by = blockIdx.y, bx = blockIdx.x;
  const int n0 = bx*128;
  const int m0 = by*128;

  f32x4_t acc[4][4];
  #pragma unroll
  for (int i=0;i<4;i++)
    #pragma unroll
    for (int j=0;j<4;j++){ f32x4_t z = {0.f,0.f,0.f,0.f}; acc[i][j] = z; }

  const long abase = (long)(srcT0 + sdir*by)*128;  // XA==0 source-row base
  const int srow = l >> 2;                         // lane row within 16-row group
  const int scol = (l & 3)*8;                      // lane col (u16)

  for (int k0 = 0; k0 < K; k0 += 32){
    __syncthreads();
    if (XA == 0){
      const u16* A = (const u16*)Av;
      #pragma unroll
      for (int c=0;c<2;c++){
        const int rb = wid*16 + c*64;              // wave-uniform row base
        __builtin_amdgcn_global_load_lds(
          (const __attribute__((address_space(1))) void*)
              (A + (abase + rb + srow)*(long)K + k0 + scol),
          (__attribute__((address_space(3))) void*)(&As[rb*32]),
          16, 0, 0);
      }
    } else {
      const float* A = (const float*)Av;
      const int xT = srcT0 + sdir*by;
      const int r0 = tid >> 2, c0 = (tid & 3)*8;
      #pragma unroll
      for (int c=0;c<2;c++){
        int row = r0 + c*64;
        const float* src = A + ((long)row*1024 + xT)*128 + k0 + c0;
        float4 f0 = *(const float4*)src;
        float4 f1 = *(const float4*)(src + 4);
        s16x8_t pk;
        pk[0]=(short)f2bf(f0.x); pk[1]=(short)f2bf(f0.y);
        pk[2]=(short)f2bf(f0.z); pk[3]=(short)f2bf(f0.w);
        pk[4]=(short)f2bf(f1.x); pk[5]=(short)f2bf(f1.y);
        pk[6]=(short)f2bf(f1.z); pk[7]=(short)f2bf(f1.w);
        *(s16x8_t*)(&As[row*32 + c0]) = pk;
      }
    }
    #pragma unroll
    for (int c=0;c<2;c++){
      const int rb = wid*16 + c*64;
      __builtin_amdgcn_global_load_lds(
        (const __attribute__((address_space(1))) void*)
            (W + (long)(n0 + rb + srow)*K + k0 + scol),
        (__attribute__((address_space(3))) void*)(&Ws[rb*32]),
        16, 0, 0);
    }
    __syncthreads();   // drains vmcnt (gload_lds) + lgkmcnt (XA=1 ds_write)

    V8 af[4], bfr[4];
    #pragma unroll
    for (int i=0;i<4;i++)
      af[i].s = *(const s16x8_t*)(&As[(wm + i*16 + lr)*32 + lg*8]);
    #pragma unroll
    for (int j=0;j<4;j++)
      bfr[j].s = *(const s16x8_t*)(&Ws[(wn + j*16 + lr)*32 + lg*8]);
    #pragma unroll
    for (int i=0;i<4;i++)
      #pragma unroll
      for (int j=0;j<4;j++)
        acc[i][j] = __builtin_amdgcn_mfma_f32_16x16x32_bf16(af[i].b, bfr[j].b, acc[i][j], 0,0,0);
  }

  #pragma unroll
  for (int i=0;i<4;i++){
    #pragma unroll
    for (int j=0;j<4;j++){
      if (OM == 0){
        int col = n0 + wn + j*16 + lr;
        float bb = bias1 ? bias1[col] : 0.f;
        if (bias2) bb += bias2[col];
        #pragma unroll
        for (int r=0;r<4;r++){
          int mrow = m0 + wm + i*16 + lg*4 + r;
          C[(long)mrow*N + col] = f2bf(acc[i][j][r] + bb);
        }
      } else {
        int colb = n0 + wn + j*16;          // multiple of 16
        int col = colb + lr;
        int g   = colb >> 8;                // gate
        int w2  = (colb >> 4) & 15;         // h-col tile within gate
        int slice = (wm >> 4) + i;          // batch-slice (row>>4)
        float bb = bias1[col] + bias2[col];
        u16x4_t v;
        #pragma unroll
        for (int r=0;r<4;r++) v[r] = f2bf(acc[i][j][r] + bb);
        long dst = (((long)by*8 + slice)*16 + w2)*1024
                 + (long)(lg*16 + lr)*16 + g*4;
        *(u16x4_t*)(C + dst) = v;
      }
    }
  }
}

// ---------------------------------------------------------------- recurrence
// r10: ONE 1024-thread block (16 waves) per (dir,slice) -> 16 blocks total.
// Wave w owns h-cols [w*16,(w+1)*16) for all 4 gates: fragments nt=g*16+w,
// kt=0..7 -> bw[4][8] = 128 VGPRs/lane, register-resident (static indices).
// h exchange is now PURE LDS + one __syncthreads per step: no cross-block
// communication, no atomics, no markers, no retries (r8's LLC round trips
// + marker-retry were ~6000 of the 8000 cy/step).
__global__ __launch_bounds__(1024, 4) void lstm_rec9(
    const u16* __restrict__ pre0, const u16* __restrict__ pre1,
    const u16* __restrict__ wf0, const u16* __restrict__ wf1,
    const float* __restrict__ wt0, const float* __restrict__ wt1,
    u16* __restrict__ out,      // rows (outBase+t)*128+b, 512 cols
    int outBase, int CT, int isFirst,
    u16* __restrict__ hstate,   // [dir][128][256] bf16
    float* __restrict__ cstate) // [dir*8+slice][1024][4] f32
{
  const int p = blockIdx.x;           // dir*8 + slice
  const int dir = p >> 3, slice = p & 7;
  const int tid = threadIdx.x;
  const int l = tid & 63, w = tid >> 6;     // w in [0,16)
  const int lr = l & 15, lg = l >> 4;

  const u16*   wf  = dir ? wf1 : wf0;
  const float* wtg = dir ? wt1 : wt0;
  const u16*   pre = dir ? pre1 : pre0;

  // ---- weights resident: 4 gates x 8 kt = 32 fragments = 128 regs/lane.
  V8 bw[4][8];
  #pragma unroll
  for (int g=0; g<4; g++){
    const int nt = g*16 + w;
    const u16* base = wf + ((long)nt*8*64 + l)*8;
    #pragma unroll
    for (int kt=0; kt<8; kt++)
      bw[g][kt].s = *(const s16x8_t*)(base + (long)kt*64*8);
  }

  __shared__ u16 h_buf[2][16][264];   // full h (256 cols), double-buffered, pad 8

  const int cr = tid >> 6, cc4 = (tid & 63)*4;   // copy mapping: 16 rows x 256 cols
  u64 h0v = 0;
  if (!isFirst)
    h0v = *(const u64*)(hstate + dir*32768 + (slice*16 + cr)*256 + cc4);
  *(u64*)&h_buf[0][cr][cc4] = h0v;

  float c[4], hacc[4] = {0,0,0,0}, cacc[4] = {0,0,0,0};
  {
    const long cb = ((long)p*1024 + tid)*4;
    #pragma unroll
    for (int r=0;r<4;r++) c[r] = isFirst ? 0.f : cstate[cb + r];
  }
  float wreg[8];
  #pragma unroll
  for (int i=0;i<8;i++) wreg[i] = wtg[i];

  __syncthreads();   // h_buf[0] ready

  // packed pre base for this (slice,w,lane): 32B contiguous per step
  const u16* preT = pre + ((long)slice*16 + w)*1024 + (long)l*16;
  s16x8_t pfA = *(const s16x8_t*)(preT);
  s16x8_t pfB = *(const s16x8_t*)(preT + 8);

  for (int t = 0; t < CT; t++){
    // acc init from packed pre (bf16 -> f32); g0,g1 from pfA, g2,g3 from pfB
    f32x4_t acc[4];
    #pragma unroll
    for (int r=0; r<4; r++){
      acc[0][r] = bf2f((u16)pfA[r]);
      acc[1][r] = bf2f((u16)pfA[4+r]);
      acc[2][r] = bf2f((u16)pfB[r]);
      acc[3][r] = bf2f((u16)pfB[4+r]);
    }
    if (t + 1 < CT){
      const u16* pp = preT + (long)(t+1)*131072;
      pfA = *(const s16x8_t*)(pp);
      pfB = *(const s16x8_t*)(pp + 8);
    }

    // ---- full-K MFMAs: h from LDS, weights from registers.
    // acc[g] chains over kt; 4 independent gate-chains pipeline the MFMA unit.
    #pragma unroll
    for (int kt=0; kt<8; kt++){
      V8 af;
      af.s = *(const s16x8_t*)(&h_buf[t&1][lr][kt*32 + lg*8]);
      #pragma unroll
      for (int g=0; g<4; g++)
        acc[g] = __builtin_amdgcn_mfma_f32_16x16x32_bf16(
            af.b, bw[g][kt].b, acc[g], 0,0,0);
    }

    // ---- gates + state update (lane-local: 4 rows of one h-col)
    const float wtv = wreg[t & 7];
    const bool last = (t & 7) == 7;
    float hout[4];
    #pragma unroll
    for (int r=0;r<4;r++){
      float iv = sigmoidf_(acc[0][r]);
      float fv = sigmoidf_(acc[1][r]);
      float gv = tanhf_  (acc[2][r]);
      float ov = sigmoidf_(acc[3][r]);
      float cn = fv*c[r] + iv*gv;
      float hh = ov*tanhf_(cn);
      float ha = hacc[r] + wtv*hh;
      float ca = cacc[r] + wtv*cn;
      hout[r] = last ? ha : hh;
      c[r]    = last ? ca : cn;
      hacc[r] = last ? 0.f : ha;
      cacc[r] = last ? 0.f : ca;
    }

    // ---- h_{t+1} into the other LDS buffer; ONE barrier per step
    #pragma unroll
    for (int r=0;r<4;r++)
      h_buf[(t+1)&1][lg*4 + r][w*16 + lr] = f2bf(hout[r]);
    __syncthreads();

    // out write (coalesced 8B/thread, fire-and-forget)
    {
      u64 v = *(const u64*)&h_buf[(t+1)&1][cr][cc4];
      const long orow = (long)(outBase + t)*128 + slice*16 + cr;
      *(u64*)(out + orow*512 + dir*256 + cc4) = v;
    }
  }

  // ---- state save (CT even -> h_CT in buf[0])
  *(u64*)(hstate + dir*32768 + (slice*16 + cr)*256 + cc4)
      = *(const u64*)&h_buf[CT&1][cr][cc4];
  {
    const long cb = ((long)p*1024 + tid)*4;
    #pragma unroll
    for (int r=0;r<4;r++) cstate[cb + r] = c[r];
  }
}

// ---------------------------------------------------------------- output proj
__global__ __launch_bounds__(256) void kout(const u16* __restrict__ Ab,
    const u16* __restrict__ Wo, const float* __restrict__ bo,
    float* __restrict__ op, int chunkRow0)
{
  __shared__ u16 Ws[4096];
  __shared__ u16 Rs[32*520];
  const int tid = threadIdx.x;
  {
    int f = tid*8;
    *(s16x8_t*)&Ws[f] = *(const s16x8_t*)(Wo + f);
    *(s16x8_t*)&Ws[f+2048] = *(const s16x8_t*)(Wo + f + 2048);
  }
  const long row0 = (long)blockIdx.x*32;
  #pragma unroll
  for (int i=0;i<8;i++){
    int f = tid*8 + i*2048;
    int rr = f >> 9, cc = f & 511;
    *(s16x8_t*)&Rs[rr*520 + cc] = *(const s16x8_t*)(Ab + (row0+rr)*512 + cc);
  }
  __syncthreads();
  const int rr = tid >> 3, d = tid & 7;
  float s = bo[d];
  for (int k=0;k<512;k+=8){
    s16x8_t a = *(const s16x8_t*)&Rs[rr*520 + k];
    s16x8_t wv = *(const s16x8_t*)&Ws[d*512 + k];
    #pragma unroll
    for (int e=0;e<8;e++)
      s += bf2f((u16)a[e]) * bf2f((u16)wv[e]);
  }
  const long grow = chunkRow0 + row0 + rr;
  const int tt = (int)(grow >> 7), b2 = (int)(grow & 127);
  op[((long)b2*1024 + tt)*8 + d] = s;
}

// ---------------------------------------------------------------- log_softmax over t (dim=1)
__global__ __launch_bounds__(256) void lsm(float* __restrict__ io){
  const int b = blockIdx.x >> 3, d = blockIdx.x & 7;
  const int tid = threadIdx.x;
  __shared__ float red[4];
  float v[4];
  float mx = -3.4e38f;
  const long base = (long)b*1024*8 + d;
  #pragma unroll
  for (int i=0;i<4;i++){
    v[i] = io[base + (long)(tid + i*256)*8];
    mx = fmaxf(mx, v[i]);
  }
  #pragma unroll
  for (int off=32; off>=1; off>>=1) mx = fmaxf(mx, __shfl_down(mx, off, 64));
  if ((tid & 63) == 0) red[tid >> 6] = mx;
  __syncthreads();
  mx = fmaxf(fmaxf(red[0],red[1]), fmaxf(red[2],red[3]));
  __syncthreads();
  float s = 0.f;
  #pragma unroll
  for (int i=0;i<4;i++) s += __expf(v[i]-mx);
  #pragma unroll
  for (int off=32; off>=1; off>>=1) s += __shfl_down(s, off, 64);
  if ((tid & 63) == 0) red[tid >> 6] = s;
  __syncthreads();
  s = red[0]+red[1]+red[2]+red[3];
  float lse = mx + __logf(s);
  #pragma unroll
  for (int i=0;i<4;i++) io[base + (long)(tid + i*256)*8] = v[i] - lse;
}

// ---------------------------------------------------------------- launch
extern "C" void kernel_launch(void* const* d_in, const int* in_sizes, int n_in,
                              void* d_out, int out_size, void* d_ws, size_t ws_size,
                              hipStream_t stream){
  const float* x     = (const float*)d_in[0];
  const float* W_in  = (const float*)d_in[1];
  const float* b_in  = (const float*)d_in[2];
  const float* Wih1  = (const float*)d_in[3];
  const float* Whh1  = (const float*)d_in[4];
  const float* bih1  = (const float*)d_in[5];
  const float* bhh1  = (const float*)d_in[6];
  const float* Wih2  = (const float*)d_in[7];
  const float* Whh2  = (const float*)d_in[8];
  const float* bih2  = (const float*)d_in[9];
  const float* bhh2  = (const float*)d_in[10];
  const float* wt1   = (const float*)d_in[11];
  const float* wt2   = (const float*)d_in[12];
  const float* W_out = (const float*)d_in[13];
  const float* b_out = (const float*)d_in[14];

  auto rnd = [](size_t b){ return (b + 255) & ~(size_t)255; };

  const size_t ACT1B   = (size_t)TT*BB*512*2;       // 128 MB
  const size_t WIHB    = (size_t)GATES*INL*2;       // 1 MB
  const size_t WFRAGB  = (size_t)GATES*HIDN*2;      // 512 KB
  const size_t WINB    = (size_t)INL*DIN*2;
  const size_t WOUTB   = (size_t)DOUT*INL*2;
  const size_t HSTB    = (size_t)2*BB*HIDN*2;       // 128 KB
  const size_t CSTB    = (size_t)16*1024*4*4;       // 256 KB

  const size_t fixedB = rnd(ACT1B) + 2*rnd(WIHB) + 2*rnd(WFRAGB) + rnd(WINB)
                      + rnd(WOUTB) + rnd(HSTB) + rnd(CSTB);

  // pick largest chunk length whose budget fits ws_size
  int CT = 8;
  const int cands[8] = {1024,512,256,128,64,32,16,8};
  for (int ci = 0; ci < 8; ci++){
    int cand = cands[ci];
    size_t need = fixedB + rnd((size_t)cand*BB*512*2) + 2*rnd((size_t)cand*BB*GATES*2);
    if (need <= ws_size){ CT = cand; break; }
  }
  const int nc = TT / CT;

  char* ws = (char*)d_ws;
  size_t off = 0;
  auto alloc = [&](size_t bytes) -> void* {
    void* p = ws + off;
    off += rnd(bytes);
    return p;
  };

  u16*   act1    = (u16*)alloc(ACT1B);
  u16*   Wihb0   = (u16*)alloc(WIHB);
  u16*   Wihb1   = (u16*)alloc(WIHB);
  u16*   wfrag0  = (u16*)alloc(WFRAGB);
  u16*   wfrag1  = (u16*)alloc(WFRAGB);
  u16*   Winb    = (u16*)alloc(WINB);
  u16*   Woutb   = (u16*)alloc(WOUTB);
  u16*   hstate  = (u16*)alloc(HSTB);
  float* cstate  = (float*)alloc(CSTB);
  u16*   actchunk= (u16*)alloc((size_t)CT*BB*512*2);
  u16*   pre0    = (u16*)alloc((size_t)CT*BB*GATES*2);
  u16*   pre1    = (u16*)alloc((size_t)CT*BB*GATES*2);

  // weight converts + packs
  cvt_f32_bf16<<<(GATES*INL/4 + 255)/256, 256, 0, stream>>>(Wih1, Wihb0, GATES*INL/4);
  cvt_f32_bf16<<<(GATES*INL/4 + 255)/256, 256, 0, stream>>>(Wih2, Wihb1, GATES*INL/4);
  cvt_f32_bf16<<<(INL*DIN/4 + 255)/256, 256, 0, stream>>>(W_in, Winb, INL*DIN/4);
  cvt_f32_bf16<<<(DOUT*INL/4 + 255)/256, 256, 0, stream>>>(W_out, Woutb, DOUT*INL/4);
  pack_whh<<<128, 256, 0, stream>>>(Whh1, wfrag0);
  pack_whh<<<128, 256, 0, stream>>>(Whh2, wfrag1);

  // ---- layer 1 (input proj recomputed per chunk from x)
  for (int c2 = 0; c2 < nc; c2++){
    gemm_tile<1,0><<<dim3(4, CT), 256, 0, stream>>>(x, Winb, actchunk,
        b_in, nullptr, DIN, 512, c2*CT, 1);
    gemm_tile<0,1><<<dim3(8, CT), 256, 0, stream>>>(actchunk, Wihb0, pre0,
        bih1, bhh1, INL, GATES, 0, 1);
    gemm_tile<1,0><<<dim3(4, CT), 256, 0, stream>>>(x, Winb, actchunk,
        b_in, nullptr, DIN, 512, 1023 - c2*CT, -1);
    gemm_tile<0,1><<<dim3(8, CT), 256, 0, stream>>>(actchunk, Wihb1, pre1,
        bih2, bhh2, INL, GATES, 0, 1);
    lstm_rec9<<<dim3(16), 1024, 0, stream>>>(pre0, pre1, wfrag0, wfrag1,
        wt1, wt2, act1, c2*CT, CT, c2 == 0, hstate, cstate);
  }

  // ---- layer 2 (reads act1; output chunk -> fused small out-proj)
  for (int c2 = 0; c2 < nc; c2++){
    gemm_tile<0,1><<<dim3(8, CT), 256, 0, stream>>>(act1, Wihb0, pre0,
        bih1, bhh1, INL, GATES, c2*CT, 1);
    gemm_tile<0,1><<<dim3(8, CT), 256, 0, stream>>>(act1, Wihb1, pre1,
        bih2, bhh2, INL, GATES, 1023 - c2*CT, -1);
    lstm_rec9<<<dim3(16), 1024, 0, stream>>>(pre0, pre1, wfrag0, wfrag1,
        wt1, wt2, actchunk, 0, CT, c2 == 0, hstate, cstate);
    kout<<<CT*4, 256, 0, stream>>>(actchunk, Woutb, b_out,
        (float*)d_out, c2*CT*128);
  }

  lsm<<<BB*DOUT, 256, 0, stream>>>((float*)d_out);
}

// Round 11
// 8696.509 us; speedup vs baseline: 2.5399x; 2.5399x over previous
//
#include <hip/hip_runtime.h>
#include <stdint.h>
#include <stddef.h>

// Problem constants (from reference)
#define HIDN 256
#define GATES 1024
#define INL 512
#define BB 128
#define TT 1024
#define TSS 8
#define DIN 128
#define DOUT 8

typedef unsigned short u16;
typedef unsigned int u32;
typedef unsigned long long u64;
typedef __bf16 bf16x8_t __attribute__((ext_vector_type(8)));
typedef float f32x4_t __attribute__((ext_vector_type(4)));
typedef short s16x8_t __attribute__((ext_vector_type(8)));
typedef u16 u16x4_t __attribute__((ext_vector_type(4)));

union V8 { s16x8_t s; bf16x8_t b; };
union U64x2 { u64 q[2]; s16x8_t s; };

#define MRK 0x0001000100010001ull   // bf16-LSB marker bits in a u64 (4 bf16)

__device__ __forceinline__ u16 f2bf(float f){
  unsigned u = __builtin_bit_cast(unsigned, f);
  u += 0x7FFFu + ((u >> 16) & 1u);
  return (u16)(u >> 16);
}
__device__ __forceinline__ float bf2f(u16 h){
  unsigned u = ((unsigned)h) << 16;
  return __builtin_bit_cast(float, u);
}
__device__ __forceinline__ float sigmoidf_(float x){ return 1.f/(1.f + __expf(-x)); }
__device__ __forceinline__ float tanhf_(float x){
  float ax = fabsf(x);
  float e = __expf(-2.f*ax);          // no overflow for any x
  float t = (1.f - e)/(1.f + e);
  return x < 0.f ? -t : t;
}

// ---------------------------------------------------------------- converts
__global__ __launch_bounds__(256) void cvt_f32_bf16(const float* __restrict__ in,
                                                    u16* __restrict__ out, int n4){
  int i = blockIdx.x*256 + threadIdx.x;
  if (i < n4){
    float4 f = ((const float4*)in)[i];
    u16x4_t u;
    u[0] = f2bf(f.x); u[1] = f2bf(f.y); u[2] = f2bf(f.z); u[3] = f2bf(f.w);
    ((u16x4_t*)out)[i] = u;
  }
}

// Pack Whh [1024][256] f32 into MFMA B-fragment order (bf16):
// frag (nt,kt): lane l, elem e -> Whh[nt*16 + (l&15)][kt*32 + (l>>4)*8 + e]
__global__ __launch_bounds__(256) void pack_whh(const float* __restrict__ Whh,
                                                u16* __restrict__ wf){
  int idx = blockIdx.x*256 + threadIdx.x;     // 32768 total
  int l  = idx & 63;
  int kt = (idx >> 6) & 7;
  int nt = idx >> 9;
  int j = nt*16 + (l & 15);
  int k = kt*32 + (l >> 4)*8;
  const float* src = Whh + (long)j*HIDN + k;
  s16x8_t pk;
  #pragma unroll
  for (int e=0;e<8;e++) pk[e] = (short)f2bf(src[e]);
  *(s16x8_t*)(wf + (long)idx*8) = pk;
}

// ---------------------------------------------------------------- GEMM
// C[M][N] = A[M][K] @ W[N][K]^T (+bias1+bias2), fp32 accum, bf16 out.
// global_load_lds width-16 staging, LINEAR LDS [128][32] (m97 structure).
// XA=0: A bf16, source row = (srcT0 + sdir*by)*128 + row (row stride K)
// XA=1: A = x f32 [B=128][T=1024][128]; source row = row*1024 + (srcT0+sdir*by)
// OM=0: plain rows C[(by*128+row)*N + col]
// OM=1: packed for lstm_rec10: (((t*8+slice)*2+hb)*8+w)*1024 + l*16 + g*4+r
template<int XA, int OM>
__global__ __launch_bounds__(256, 2) void gemm_tile(
    const void* __restrict__ Av, const u16* __restrict__ W,
    u16* __restrict__ C,
    const float* __restrict__ bias1, const float* __restrict__ bias2,
    int K, int N, int srcT0, int sdir)
{
  __shared__ u16 As[128*32];
  __shared__ u16 Ws[128*32];
  const int tid = threadIdx.x;
  const int l = tid & 63, wid = tid >> 6;
  const int lr = l & 15, lg = l >> 4;
  const int wm = (wid >> 1)*64, wn = (wid & 1)*64;
  const int by = blockIdx.y, bx = blockIdx.x;
  const int n0 = bx*128;
  const int m0 = by*128;

  f32x4_t acc[4][4];
  #pragma unroll
  for (int i=0;i<4;i++)
    #pragma unroll
    for (int j=0;j<4;j++){ f32x4_t z = {0.f,0.f,0.f,0.f}; acc[i][j] = z; }

  const long abase = (long)(srcT0 + sdir*by)*128;  // XA==0 source-row base
  const int srow = l >> 2;                         // lane row within 16-row group
  const int scol = (l & 3)*8;                      // lane col (u16)

  for (int k0 = 0; k0 < K; k0 += 32){
    __syncthreads();
    if (XA == 0){
      const u16* A = (const u16*)Av;
      #pragma unroll
      for (int c=0;c<2;c++){
        const int rb = wid*16 + c*64;              // wave-uniform row base
        __builtin_amdgcn_global_load_lds(
          (const __attribute__((address_space(1))) void*)
              (A + (abase + rb + srow)*(long)K + k0 + scol),
          (__attribute__((address_space(3))) void*)(&As[rb*32]),
          16, 0, 0);
      }
    } else {
      const float* A = (const float*)Av;
      const int xT = srcT0 + sdir*by;
      const int r0 = tid >> 2, c0 = (tid & 3)*8;
      #pragma unroll
      for (int c=0;c<2;c++){
        int row = r0 + c*64;
        const float* src = A + ((long)row*1024 + xT)*128 + k0 + c0;
        float4 f0 = *(const float4*)src;
        float4 f1 = *(const float4*)(src + 4);
        s16x8_t pk;
        pk[0]=(short)f2bf(f0.x); pk[1]=(short)f2bf(f0.y);
        pk[2]=(short)f2bf(f0.z); pk[3]=(short)f2bf(f0.w);
        pk[4]=(short)f2bf(f1.x); pk[5]=(short)f2bf(f1.y);
        pk[6]=(short)f2bf(f1.z); pk[7]=(short)f2bf(f1.w);
        *(s16x8_t*)(&As[row*32 + c0]) = pk;
      }
    }
    #pragma unroll
    for (int c=0;c<2;c++){
      const int rb = wid*16 + c*64;
      __builtin_amdgcn_global_load_lds(
        (const __attribute__((address_space(1))) void*)
            (W + (long)(n0 + rb + srow)*K + k0 + scol),
        (__attribute__((address_space(3))) void*)(&Ws[rb*32]),
        16, 0, 0);
    }
    __syncthreads();   // drains vmcnt (gload_lds) + lgkmcnt (XA=1 ds_write)

    V8 af[4], bfr[4];
    #pragma unroll
    for (int i=0;i<4;i++)
      af[i].s = *(const s16x8_t*)(&As[(wm + i*16 + lr)*32 + lg*8]);
    #pragma unroll
    for (int j=0;j<4;j++)
      bfr[j].s = *(const s16x8_t*)(&Ws[(wn + j*16 + lr)*32 + lg*8]);
    #pragma unroll
    for (int i=0;i<4;i++)
      #pragma unroll
      for (int j=0;j<4;j++)
        acc[i][j] = __builtin_amdgcn_mfma_f32_16x16x32_bf16(af[i].b, bfr[j].b, acc[i][j], 0,0,0);
  }

  #pragma unroll
  for (int i=0;i<4;i++){
    #pragma unroll
    for (int j=0;j<4;j++){
      if (OM == 0){
        int col = n0 + wn + j*16 + lr;
        float bb = bias1 ? bias1[col] : 0.f;
        if (bias2) bb += bias2[col];
        #pragma unroll
        for (int r=0;r<4;r++){
          int mrow = m0 + wm + i*16 + lg*4 + r;
          C[(long)mrow*N + col] = f2bf(acc[i][j][r] + bb);
        }
      } else {
        int colb = n0 + wn + j*16;          // multiple of 16
        int col = colb + lr;
        int g   = colb >> 8;
        int hb2 = (colb >> 7) & 1;
        int w2  = (colb >> 4) & 7;
        int slice = (wm >> 4) + i;
        float bb = bias1[col] + bias2[col];
        u16x4_t v;
        #pragma unroll
        for (int r=0;r<4;r++) v[r] = f2bf(acc[i][j][r] + bb);
        long dst = ((((long)by*8 + slice)*2 + hb2)*8 + w2)*1024
                 + (long)l*16 + g*4;
        *(u16x4_t*)(C + dst) = v;
      }
    }
  }
}

// ---------------------------------------------------------------- recurrence
// r11 = r8 structure (32 blocks: bid = hb*16 + dir*8 + slice; weights
// register-resident; in-band bf16-LSB step-parity markers) with two
// exchange-latency fixes:
//  A) publish IMMEDIATELY after gates via 4 scattered marked 2B atomic
//     stores from compute-mapping registers (skips LDS round trip +
//     barrier skew on the visibility path; per-bf16 markers make partial
//     arrival self-detecting).
//  B) consumer polls ONE canary u64 (512B/wave vs 4KB) in a tight spin,
//     then bulk-loads the rest once; rare full retry. 8x less LLC poll
//     traffic, one detect latency instead of repeated full reloads.
__global__ __launch_bounds__(512, 2) void lstm_rec10(
    const u16* __restrict__ pre0, const u16* __restrict__ pre1,
    const u16* __restrict__ wf0, const u16* __restrict__ wf1,
    const float* __restrict__ wt0, const float* __restrict__ wt1,
    u16* __restrict__ out,      // rows (outBase+t)*128+b, 512 cols
    int outBase, int CT, int isFirst,
    u16* __restrict__ hstate,   // [dir][128][256] bf16
    float* __restrict__ cstate, // [dir*16+slice*2+hb][512][4] f32
    u16* __restrict__ hx)       // [p*2+hb][slot(2)][16][128] bf16 (marked)
{
  const int bid = blockIdx.x;
  const int hb  = bid >> 4;
  const int p   = bid & 15;
  const int dir = p >> 3, slice = p & 7;
  const int tid = threadIdx.x;
  const int l = tid & 63, w = tid >> 6;
  const int lr = l & 15, lg = l >> 4;

  const u16*   wf  = dir ? wf1 : wf0;
  const float* wtg = dir ? wt1 : wt0;
  const u16*   pre = dir ? pre1 : pre0;

  // ---- weights resident: 32 fragments = 128 regs/lane, STATIC indices only.
  V8 bwOwn[4][4], bwPeer[4][4];
  #pragma unroll
  for (int g=0; g<4; g++){
    const int nt = g*16 + hb*8 + w;
    const u16* base = wf + ((long)nt*8*64 + l)*8;
    const long ownOff  = (long)(hb*4)*64*8;
    const long peerOff = (long)((1-hb)*4)*64*8;
    #pragma unroll
    for (int j=0; j<4; j++){
      bwOwn [g][j].s = *(const s16x8_t*)(base + ownOff  + (long)j*64*8);
      bwPeer[g][j].s = *(const s16x8_t*)(base + peerOff + (long)j*64*8);
    }
  }

  __shared__ u16 h_buf[2][16][136];   // double-buffered own half (local cols)

  const int cr = tid >> 5, cc4 = (tid & 31)*4;   // copy-thread mapping
  u64 h0v = 0;
  if (!isFirst){
    const u16* src = hstate + dir*32768 + (slice*16 + cr)*256 + hb*128 + cc4;
    h0v = *(const u64*)src;
  }
  *(u64*)&h_buf[0][cr][cc4] = h0v;
  float c[4], hacc[4] = {0,0,0,0}, cacc[4] = {0,0,0,0};
  {
    const long cb = ((long)(dir*16 + slice*2 + hb)*512 + tid)*4;
    #pragma unroll
    for (int r=0;r<4;r++) c[r] = isFirst ? 0.f : cstate[cb + r];
  }
  float wreg[8];
  #pragma unroll
  for (int i=0;i<8;i++) wreg[i] = wtg[i];

  u16*       myx   = hx + (long)(p*2 + hb)*2*2048;
  const u16* peerx = hx + (long)(p*2 + (1-hb))*2*2048;

  // prologue publish: h_0 into slot 0 with parity 0 (clear LSBs); no drain
  __hip_atomic_store((u64*)(myx + cr*128 + cc4), h0v & ~MRK,
                     __ATOMIC_RELAXED, __HIP_MEMORY_SCOPE_AGENT);
  __syncthreads();   // h_buf[0] visible to all waves

  // scatter-publish base (compute mapping): col = w*16+lr, rows lg*4+r
  const int pubCol = w*16 + lr;

  // packed pre base for this (slice,hb,w,lane): 32B contiguous per step
  const u16* preT = pre + (((long)slice*2 + hb)*8 + w)*1024 + (long)l*16;
  s16x8_t pfA = *(const s16x8_t*)(preT);
  s16x8_t pfB = *(const s16x8_t*)(preT + 8);

  for (int t = 0; t < CT; t++){
    // acc init from packed pre (bf16 -> f32)
    f32x4_t acc[4];
    #pragma unroll
    for (int r=0; r<4; r++){
      acc[0][r] = bf2f((u16)pfA[r]);
      acc[1][r] = bf2f((u16)pfA[4+r]);
      acc[2][r] = bf2f((u16)pfB[r]);
      acc[3][r] = bf2f((u16)pfB[4+r]);
    }
    if (t + 1 < CT){
      const u16* pp = preT + (long)(t+1)*131072;
      pfA = *(const s16x8_t*)(pp);
      pfB = *(const s16x8_t*)(pp + 8);
    }

    const u64 exp = ((t>>1)&1) ? MRK : 0ull;
    const u64* qb = (const u64*)(peerx + (long)(t&1)*2048) + (lr*32 + lg*2);

    // canary load issued before own-MFMA (overlaps MFMA latency)
    u64 q0 = __hip_atomic_load(qb, __ATOMIC_RELAXED, __HIP_MEMORY_SCOPE_AGENT);

    // ---- own-half K MFMAs (h_own from LDS) — independent of q0
    {
      V8 af[4];
      const u16* hb0 = &h_buf[t&1][lr][lg*8];
      #pragma unroll
      for (int j=0;j<4;j++)
        af[j].s = *(const s16x8_t*)(hb0 + j*32);
      #pragma unroll
      for (int g=0;g<4;g++)
        #pragma unroll
        for (int j=0;j<4;j++)
          acc[g] = __builtin_amdgcn_mfma_f32_16x16x32_bf16(
              af[j].b, bwOwn[g][j].b, acc[g], 0,0,0);
    }

    // ---- spin on the canary only (512B/wave per poll)
    {
      int tries = 0;
      while (!__all((q0 & MRK) == exp)){
        if (++tries > (1<<16)) break;    // fail loud (wrong result), not hang
        __builtin_amdgcn_s_sleep(1);
        q0 = __hip_atomic_load(qb, __ATOMIC_RELAXED, __HIP_MEMORY_SCOPE_AGENT);
      }
    }
    asm volatile("" ::: "memory");   // pin the bulk loads after the spin

    // ---- bulk-load remaining 7 u64 + validate all; rare full retry
    u64 q[8];
    q[0] = q0;
    #pragma unroll
    for (int j=0;j<4;j++)
      #pragma unroll
      for (int k=0;k<2;k++)
        if (j || k)
          q[j*2+k] = __hip_atomic_load(qb + j*8 + k,
                        __ATOMIC_RELAXED, __HIP_MEMORY_SCOPE_AGENT);
    {
      int tries = 0;
      while (true){
        int ok = 1;
        #pragma unroll
        for (int i=0;i<8;i++) ok &= ((q[i] & MRK) == exp);
        if (__all(ok)) break;
        if (++tries > (1<<16)) break;
        __builtin_amdgcn_s_sleep(1);
        #pragma unroll
        for (int j=0;j<4;j++)
          #pragma unroll
          for (int k=0;k<2;k++)
            q[j*2+k] = __hip_atomic_load(qb + j*8 + k,
                          __ATOMIC_RELAXED, __HIP_MEMORY_SCOPE_AGENT);
      }
    }
    // ---- peer-half K MFMAs
    {
      V8 pafr[4];
      #pragma unroll
      for (int j=0;j<4;j++){
        U64x2 uq;
        uq.q[0] = q[j*2]; uq.q[1] = q[j*2+1];
        pafr[j].s = uq.s;
      }
      #pragma unroll
      for (int g=0;g<4;g++)
        #pragma unroll
        for (int j=0;j<4;j++)
          acc[g] = __builtin_amdgcn_mfma_f32_16x16x32_bf16(
              pafr[j].b, bwPeer[g][j].b, acc[g], 0,0,0);
    }

    // ---- gates + state update (lane-local: 4 rows of one h-col)
    const float wtv = wreg[t & 7];
    const bool last = (t & 7) == 7;
    float hout[4];
    #pragma unroll
    for (int r=0;r<4;r++){
      float iv = sigmoidf_(acc[0][r]);
      float fv = sigmoidf_(acc[1][r]);
      float gv = tanhf_  (acc[2][r]);
      float ov = sigmoidf_(acc[3][r]);
      float cn = fv*c[r] + iv*gv;
      float hh = ov*tanhf_(cn);
      float ha = hacc[r] + wtv*hh;
      float ca = cacc[r] + wtv*cn;
      hout[r] = last ? ha : hh;
      c[r]    = last ? ca : cn;
      hacc[r] = last ? 0.f : ha;
      cacc[r] = last ? 0.f : ca;
    }

    // ---- EARLY publish: 4 scattered marked 2B stores straight from regs
    //      (visibility path skips LDS write + barrier)
    u16 hb16[4];
    #pragma unroll
    for (int r=0;r<4;r++) hb16[r] = f2bf(hout[r]);
    if (t < CT - 1){
      const u16 pm1 = (u16)((((t+1)>>1)&1));
      u16* dst = myx + (long)((t+1)&1)*2048 + pubCol;
      #pragma unroll
      for (int r=0;r<4;r++){
        u16 v = (u16)((hb16[r] & 0xFFFEu) | pm1);
        __hip_atomic_store(dst + (lg*4+r)*128, v,
                           __ATOMIC_RELAXED, __HIP_MEMORY_SCOPE_AGENT);
      }
    }

    // ---- own h_{t+1} into the other LDS buffer; single barrier per step
    #pragma unroll
    for (int r=0;r<4;r++)
      h_buf[(t+1)&1][lg*4 + r][pubCol] = hb16[r];
    __syncthreads();

    // out write (coalesced u64, fire-and-forget, off critical path)
    {
      u16x4_t v = *(const u16x4_t*)&h_buf[(t+1)&1][cr][cc4];
      const long orow = (long)(outBase + t)*128 + slice*16 + cr;
      *(u16x4_t*)(out + orow*512 + dir*256 + hb*128 + cc4) = v;
    }
  }

  // ---- state save (CT even -> h_CT in buf[0])
  {
    u16* dst = hstate + dir*32768 + (slice*16 + cr)*256 + hb*128 + cc4;
    *(u16x4_t*)dst = *(const u16x4_t*)&h_buf[CT&1][cr][cc4];
  }
  {
    const long cb = ((long)(dir*16 + slice*2 + hb)*512 + tid)*4;
    #pragma unroll
    for (int r=0;r<4;r++) cstate[cb + r] = c[r];
  }
}

// ---------------------------------------------------------------- output proj
__global__ __launch_bounds__(256) void kout(const u16* __restrict__ Ab,
    const u16* __restrict__ Wo, const float* __restrict__ bo,
    float* __restrict__ op, int chunkRow0)
{
  __shared__ u16 Ws[4096];
  __shared__ u16 Rs[32*520];
  const int tid = threadIdx.x;
  {
    int f = tid*8;
    *(s16x8_t*)&Ws[f] = *(const s16x8_t*)(Wo + f);
    *(s16x8_t*)&Ws[f+2048] = *(const s16x8_t*)(Wo + f + 2048);
  }
  const long row0 = (long)blockIdx.x*32;
  #pragma unroll
  for (int i=0;i<8;i++){
    int f = tid*8 + i*2048;
    int rr = f >> 9, cc = f & 511;
    *(s16x8_t*)&Rs[rr*520 + cc] = *(const s16x8_t*)(Ab + (row0+rr)*512 + cc);
  }
  __syncthreads();
  const int rr = tid >> 3, d = tid & 7;
  float s = bo[d];
  for (int k=0;k<512;k+=8){
    s16x8_t a = *(const s16x8_t*)&Rs[rr*520 + k];
    s16x8_t wv = *(const s16x8_t*)&Ws[d*512 + k];
    #pragma unroll
    for (int e=0;e<8;e++)
      s += bf2f((u16)a[e]) * bf2f((u16)wv[e]);
  }
  const long grow = chunkRow0 + row0 + rr;
  const int tt = (int)(grow >> 7), b2 = (int)(grow & 127);
  op[((long)b2*1024 + tt)*8 + d] = s;
}

// ---------------------------------------------------------------- log_softmax over t (dim=1)
__global__ __launch_bounds__(256) void lsm(float* __restrict__ io){
  const int b = blockIdx.x >> 3, d = blockIdx.x & 7;
  const int tid = threadIdx.x;
  __shared__ float red[4];
  float v[4];
  float mx = -3.4e38f;
  const long base = (long)b*1024*8 + d;
  #pragma unroll
  for (int i=0;i<4;i++){
    v[i] = io[base + (long)(tid + i*256)*8];
    mx = fmaxf(mx, v[i]);
  }
  #pragma unroll
  for (int off=32; off>=1; off>>=1) mx = fmaxf(mx, __shfl_down(mx, off, 64));
  if ((tid & 63) == 0) red[tid >> 6] = mx;
  __syncthreads();
  mx = fmaxf(fmaxf(red[0],red[1]), fmaxf(red[2],red[3]));
  __syncthreads();
  float s = 0.f;
  #pragma unroll
  for (int i=0;i<4;i++) s += __expf(v[i]-mx);
  #pragma unroll
  for (int off=32; off>=1; off>>=1) s += __shfl_down(s, off, 64);
  if ((tid & 63) == 0) red[tid >> 6] = s;
  __syncthreads();
  s = red[0]+red[1]+red[2]+red[3];
  float lse = mx + __logf(s);
  #pragma unroll
  for (int i=0;i<4;i++) io[base + (long)(tid + i*256)*8] = v[i] - lse;
}

// ---------------------------------------------------------------- launch
extern "C" void kernel_launch(void* const* d_in, const int* in_sizes, int n_in,
                              void* d_out, int out_size, void* d_ws, size_t ws_size,
                              hipStream_t stream){
  const float* x     = (const float*)d_in[0];
  const float* W_in  = (const float*)d_in[1];
  const float* b_in  = (const float*)d_in[2];
  const float* Wih1  = (const float*)d_in[3];
  const float* Whh1  = (const float*)d_in[4];
  const float* bih1  = (const float*)d_in[5];
  const float* bhh1  = (const float*)d_in[6];
  const float* Wih2  = (const float*)d_in[7];
  const float* Whh2  = (const float*)d_in[8];
  const float* bih2  = (const float*)d_in[9];
  const float* bhh2  = (const float*)d_in[10];
  const float* wt1   = (const float*)d_in[11];
  const float* wt2   = (const float*)d_in[12];
  const float* W_out = (const float*)d_in[13];
  const float* b_out = (const float*)d_in[14];

  auto rnd = [](size_t b){ return (b + 255) & ~(size_t)255; };

  const size_t ACT1B   = (size_t)TT*BB*512*2;       // 128 MB
  const size_t WIHB    = (size_t)GATES*INL*2;       // 1 MB
  const size_t WFRAGB  = (size_t)GATES*HIDN*2;      // 512 KB
  const size_t WINB    = (size_t)INL*DIN*2;
  const size_t WOUTB   = (size_t)DOUT*INL*2;
  const size_t HSTB    = (size_t)2*BB*HIDN*2;       // 128 KB
  const size_t CSTB    = (size_t)32*512*4*4;        // 256 KB
  const size_t HXB     = (size_t)32*2*2048*2;       // 256 KB (bf16 payload)

  const size_t fixedB = rnd(ACT1B) + 2*rnd(WIHB) + 2*rnd(WFRAGB) + rnd(WINB)
                      + rnd(WOUTB) + rnd(HSTB) + rnd(CSTB) + rnd(HXB);

  // pick largest chunk length whose budget fits ws_size (all cands ≡ 0 mod 4:
  // chunk-final publishes carry parity 1, so new-launch t=0/1 (expect 0) are
  // blocked by stale data — the marker ring is safe across launches)
  int CT = 8;
  const int cands[8] = {1024,512,256,128,64,32,16,8};
  for (int ci = 0; ci < 8; ci++){
    int cand = cands[ci];
    size_t need = fixedB + rnd((size_t)cand*BB*512*2) + 2*rnd((size_t)cand*BB*GATES*2);
    if (need <= ws_size){ CT = cand; break; }
  }
  const int nc = TT / CT;

  char* ws = (char*)d_ws;
  size_t off = 0;
  auto alloc = [&](size_t bytes) -> void* {
    void* p = ws + off;
    off += rnd(bytes);
    return p;
  };

  u16*   act1    = (u16*)alloc(ACT1B);
  u16*   Wihb0   = (u16*)alloc(WIHB);
  u16*   Wihb1   = (u16*)alloc(WIHB);
  u16*   wfrag0  = (u16*)alloc(WFRAGB);
  u16*   wfrag1  = (u16*)alloc(WFRAGB);
  u16*   Winb    = (u16*)alloc(WINB);
  u16*   Woutb   = (u16*)alloc(WOUTB);
  u16*   hstate  = (u16*)alloc(HSTB);
  float* cstate  = (float*)alloc(CSTB);
  u16*   hx      = (u16*)alloc(HXB);
  u16*   actchunk= (u16*)alloc((size_t)CT*BB*512*2);
  u16*   pre0    = (u16*)alloc((size_t)CT*BB*GATES*2);
  u16*   pre1    = (u16*)alloc((size_t)CT*BB*GATES*2);

  // invalidate exchange markers once per call: 0xFF -> every bf16 LSB = 1,
  // which never matches the parity-0 expectation of the first reads
  hipMemsetAsync(hx, 0xFF, HXB, stream);

  // weight converts + packs
  cvt_f32_bf16<<<(GATES*INL/4 + 255)/256, 256, 0, stream>>>(Wih1, Wihb0, GATES*INL/4);
  cvt_f32_bf16<<<(GATES*INL/4 + 255)/256, 256, 0, stream>>>(Wih2, Wihb1, GATES*INL/4);
  cvt_f32_bf16<<<(INL*DIN/4 + 255)/256, 256, 0, stream>>>(W_in, Winb, INL*DIN/4);
  cvt_f32_bf16<<<(DOUT*INL/4 + 255)/256, 256, 0, stream>>>(W_out, Woutb, DOUT*INL/4);
  pack_whh<<<128, 256, 0, stream>>>(Whh1, wfrag0);
  pack_whh<<<128, 256, 0, stream>>>(Whh2, wfrag1);

  // ---- layer 1 (input proj recomputed per chunk from x)
  for (int c2 = 0; c2 < nc; c2++){
    gemm_tile<1,0><<<dim3(4, CT), 256, 0, stream>>>(x, Winb, actchunk,
        b_in, nullptr, DIN, 512, c2*CT, 1);
    gemm_tile<0,1><<<dim3(8, CT), 256, 0, stream>>>(actchunk, Wihb0, pre0,
        bih1, bhh1, INL, GATES, 0, 1);
    gemm_tile<1,0><<<dim3(4, CT), 256, 0, stream>>>(x, Winb, actchunk,
        b_in, nullptr, DIN, 512, 1023 - c2*CT, -1);
    gemm_tile<0,1><<<dim3(8, CT), 256, 0, stream>>>(actchunk, Wihb1, pre1,
        bih2, bhh2, INL, GATES, 0, 1);
    lstm_rec10<<<dim3(32), 512, 0, stream>>>(pre0, pre1, wfrag0, wfrag1,
        wt1, wt2, act1, c2*CT, CT, c2 == 0, hstate, cstate, hx);
  }

  // ---- layer 2 (reads act1; output chunk -> fused small out-proj)
  for (int c2 = 0; c2 < nc; c2++){
    gemm_tile<0,1><<<dim3(8, CT), 256, 0, stream>>>(act1, Wihb0, pre0,
        bih1, bhh1, INL, GATES, c2*CT, 1);
    gemm_tile<0,1><<<dim3(8, CT), 256, 0, stream>>>(act1, Wihb1, pre1,
        bih2, bhh2, INL, GATES, 1023 - c2*CT, -1);
    lstm_rec10<<<dim3(32), 512, 0, stream>>>(pre0, pre1, wfrag0, wfrag1,
        wt1, wt2, actchunk, 0, CT, c2 == 0, hstate, cstate, hx);
    kout<<<CT*4, 256, 0, stream>>>(actchunk, Woutb, b_out,
        (float*)d_out, c2*CT*128);
  }

  lsm<<<BB*DOUT, 256, 0, stream>>>((float*)d_out);
}

// Round 12
// 7886.025 us; speedup vs baseline: 2.8010x; 1.1028x over previous
//
#include <hip/hip_runtime.h>
#include <stdint.h>
#include <stddef.h>

// Problem constants (from reference)
#define HIDN 256
#define GATES 1024
#define INL 512
#define BB 128
#define TT 1024
#define TSS 8
#define DIN 128
#define DOUT 8

typedef unsigned short u16;
typedef unsigned int u32;
typedef unsigned long long u64;
typedef __bf16 bf16x8_t __attribute__((ext_vector_type(8)));
typedef float f32x4_t __attribute__((ext_vector_type(4)));
typedef short s16x8_t __attribute__((ext_vector_type(8)));
typedef u16 u16x4_t __attribute__((ext_vector_type(4)));

union V8 { s16x8_t s; bf16x8_t b; };
union Q8 { s16x8_t s; u64 q[2]; };

#define MRK 0x0001000100010001ull   // bf16-LSB marker bits in a u64 (4 bf16)

__device__ __forceinline__ u16 f2bf(float f){
  unsigned u = __builtin_bit_cast(unsigned, f);
  u += 0x7FFFu + ((u >> 16) & 1u);
  return (u16)(u >> 16);
}
__device__ __forceinline__ float bf2f(u16 h){
  unsigned u = ((unsigned)h) << 16;
  return __builtin_bit_cast(float, u);
}
__device__ __forceinline__ float sigmoidf_(float x){ return 1.f/(1.f + __expf(-x)); }
__device__ __forceinline__ float tanhf_(float x){
  float ax = fabsf(x);
  float e = __expf(-2.f*ax);          // no overflow for any x
  float t = (1.f - e)/(1.f + e);
  return x < 0.f ? -t : t;
}

// ---------------------------------------------------------------- converts
__global__ __launch_bounds__(256) void cvt_f32_bf16(const float* __restrict__ in,
                                                    u16* __restrict__ out, int n4){
  int i = blockIdx.x*256 + threadIdx.x;
  if (i < n4){
    float4 f = ((const float4*)in)[i];
    u16x4_t u;
    u[0] = f2bf(f.x); u[1] = f2bf(f.y); u[2] = f2bf(f.z); u[3] = f2bf(f.w);
    ((u16x4_t*)out)[i] = u;
  }
}

// Pack Whh [1024][256] f32 into MFMA B-fragment order (bf16):
// frag (nt,kt): lane l, elem e -> Whh[nt*16 + (l&15)][kt*32 + (l>>4)*8 + e]
__global__ __launch_bounds__(256) void pack_whh(const float* __restrict__ Whh,
                                                u16* __restrict__ wf){
  int idx = blockIdx.x*256 + threadIdx.x;     // 32768 total
  int l  = idx & 63;
  int kt = (idx >> 6) & 7;
  int nt = idx >> 9;
  int j = nt*16 + (l & 15);
  int k = kt*32 + (l >> 4)*8;
  const float* src = Whh + (long)j*HIDN + k;
  s16x8_t pk;
  #pragma unroll
  for (int e=0;e<8;e++) pk[e] = (short)f2bf(src[e]);
  *(s16x8_t*)(wf + (long)idx*8) = pk;
}

// ---------------------------------------------------------------- GEMM
// C[M][N] = A[M][K] @ W[N][K]^T (+bias1+bias2), fp32 accum, bf16 out.
// global_load_lds width-16 staging, LINEAR LDS [128][32] (m97 structure).
// XA=0: A bf16, source row = (srcT0 + sdir*by)*128 + row (row stride K)
// XA=1: A = x f32 [B=128][T=1024][128]; source row = row*1024 + (srcT0+sdir*by)
// OM=0: plain rows C[(by*128+row)*N + col]
// OM=1: packed for lstm_rec11: (((t*8+slice)*2+hb)*8+w)*1024 + l*16 + g*4+r
template<int XA, int OM>
__global__ __launch_bounds__(256, 2) void gemm_tile(
    const void* __restrict__ Av, const u16* __restrict__ W,
    u16* __restrict__ C,
    const float* __restrict__ bias1, const float* __restrict__ bias2,
    int K, int N, int srcT0, int sdir)
{
  __shared__ u16 As[128*32];
  __shared__ u16 Ws[128*32];
  const int tid = threadIdx.x;
  const int l = tid & 63, wid = tid >> 6;
  const int lr = l & 15, lg = l >> 4;
  const int wm = (wid >> 1)*64, wn = (wid & 1)*64;
  const int by = blockIdx.y, bx = blockIdx.x;
  const int n0 = bx*128;
  const int m0 = by*128;

  f32x4_t acc[4][4];
  #pragma unroll
  for (int i=0;i<4;i++)
    #pragma unroll
    for (int j=0;j<4;j++){ f32x4_t z = {0.f,0.f,0.f,0.f}; acc[i][j] = z; }

  const long abase = (long)(srcT0 + sdir*by)*128;  // XA==0 source-row base
  const int srow = l >> 2;                         // lane row within 16-row group
  const int scol = (l & 3)*8;                      // lane col (u16)

  for (int k0 = 0; k0 < K; k0 += 32){
    __syncthreads();
    if (XA == 0){
      const u16* A = (const u16*)Av;
      #pragma unroll
      for (int c=0;c<2;c++){
        const int rb = wid*16 + c*64;              // wave-uniform row base
        __builtin_amdgcn_global_load_lds(
          (const __attribute__((address_space(1))) void*)
              (A + (abase + rb + srow)*(long)K + k0 + scol),
          (__attribute__((address_space(3))) void*)(&As[rb*32]),
          16, 0, 0);
      }
    } else {
      const float* A = (const float*)Av;
      const int xT = srcT0 + sdir*by;
      const int r0 = tid >> 2, c0 = (tid & 3)*8;
      #pragma unroll
      for (int c=0;c<2;c++){
        int row = r0 + c*64;
        const float* src = A + ((long)row*1024 + xT)*128 + k0 + c0;
        float4 f0 = *(const float4*)src;
        float4 f1 = *(const float4*)(src + 4);
        s16x8_t pk;
        pk[0]=(short)f2bf(f0.x); pk[1]=(short)f2bf(f0.y);
        pk[2]=(short)f2bf(f0.z); pk[3]=(short)f2bf(f0.w);
        pk[4]=(short)f2bf(f1.x); pk[5]=(short)f2bf(f1.y);
        pk[6]=(short)f2bf(f1.z); pk[7]=(short)f2bf(f1.w);
        *(s16x8_t*)(&As[row*32 + c0]) = pk;
      }
    }
    #pragma unroll
    for (int c=0;c<2;c++){
      const int rb = wid*16 + c*64;
      __builtin_amdgcn_global_load_lds(
        (const __attribute__((address_space(1))) void*)
            (W + (long)(n0 + rb + srow)*K + k0 + scol),
        (__attribute__((address_space(3))) void*)(&Ws[rb*32]),
        16, 0, 0);
    }
    __syncthreads();   // drains vmcnt (gload_lds) + lgkmcnt (XA=1 ds_write)

    V8 af[4], bfr[4];
    #pragma unroll
    for (int i=0;i<4;i++)
      af[i].s = *(const s16x8_t*)(&As[(wm + i*16 + lr)*32 + lg*8]);
    #pragma unroll
    for (int j=0;j<4;j++)
      bfr[j].s = *(const s16x8_t*)(&Ws[(wn + j*16 + lr)*32 + lg*8]);
    #pragma unroll
    for (int i=0;i<4;i++)
      #pragma unroll
      for (int j=0;j<4;j++)
        acc[i][j] = __builtin_amdgcn_mfma_f32_16x16x32_bf16(af[i].b, bfr[j].b, acc[i][j], 0,0,0);
  }

  #pragma unroll
  for (int i=0;i<4;i++){
    #pragma unroll
    for (int j=0;j<4;j++){
      if (OM == 0){
        int col = n0 + wn + j*16 + lr;
        float bb = bias1 ? bias1[col] : 0.f;
        if (bias2) bb += bias2[col];
        #pragma unroll
        for (int r=0;r<4;r++){
          int mrow = m0 + wm + i*16 + lg*4 + r;
          C[(long)mrow*N + col] = f2bf(acc[i][j][r] + bb);
        }
      } else {
        int colb = n0 + wn + j*16;          // multiple of 16
        int col = colb + lr;
        int g   = colb >> 8;
        int hb2 = (colb >> 7) & 1;
        int w2  = (colb >> 4) & 7;
        int slice = (wm >> 4) + i;
        float bb = bias1[col] + bias2[col];
        u16x4_t v;
        #pragma unroll
        for (int r=0;r<4;r++) v[r] = f2bf(acc[i][j][r] + bb);
        long dst = ((((long)by*8 + slice)*2 + hb2)*8 + w2)*1024
                 + (long)l*16 + g*4;
        *(u16x4_t*)(C + dst) = v;
      }
    }
  }
}

// ---------------------------------------------------------------- recurrence
// r12 = r11 structure (32 blocks, register-resident weights, in-band bf16-LSB
// step-parity markers, early scatter-publish) with ONE change: the consumer's
// peer-payload read is a single inline-asm batch of 4x global_load_dwordx4
// sc0 sc1 + ONE s_waitcnt vmcnt(0), instead of 8-9 relaxed atomic loads.
// Theory: hipcc conservatively serializes atomic loads (one waitcnt each)
// -> ~8 dependent LLC round trips ~6000cy/step. Batch = one round trip.
// Early-clobber "=&v" outputs (r4's crash suspect: address/output aliasing).
__global__ __launch_bounds__(512, 2) void lstm_rec11(
    const u16* __restrict__ pre0, const u16* __restrict__ pre1,
    const u16* __restrict__ wf0, const u16* __restrict__ wf1,
    const float* __restrict__ wt0, const float* __restrict__ wt1,
    u16* __restrict__ out,      // rows (outBase+t)*128+b, 512 cols
    int outBase, int CT, int isFirst,
    u16* __restrict__ hstate,   // [dir][128][256] bf16
    float* __restrict__ cstate, // [dir*16+slice*2+hb][512][4] f32
    u16* __restrict__ hx)       // [p*2+hb][slot(2)][16][128] bf16 (marked)
{
  const int bid = blockIdx.x;
  const int hb  = bid >> 4;
  const int p   = bid & 15;
  const int dir = p >> 3, slice = p & 7;
  const int tid = threadIdx.x;
  const int l = tid & 63, w = tid >> 6;
  const int lr = l & 15, lg = l >> 4;

  const u16*   wf  = dir ? wf1 : wf0;
  const float* wtg = dir ? wt1 : wt0;
  const u16*   pre = dir ? pre1 : pre0;

  // ---- weights resident: 32 fragments = 128 regs/lane, STATIC indices only.
  V8 bwOwn[4][4], bwPeer[4][4];
  #pragma unroll
  for (int g=0; g<4; g++){
    const int nt = g*16 + hb*8 + w;
    const u16* base = wf + ((long)nt*8*64 + l)*8;
    const long ownOff  = (long)(hb*4)*64*8;
    const long peerOff = (long)((1-hb)*4)*64*8;
    #pragma unroll
    for (int j=0; j<4; j++){
      bwOwn [g][j].s = *(const s16x8_t*)(base + ownOff  + (long)j*64*8);
      bwPeer[g][j].s = *(const s16x8_t*)(base + peerOff + (long)j*64*8);
    }
  }

  __shared__ u16 h_buf[2][16][136];   // double-buffered own half (local cols)

  const int cr = tid >> 5, cc4 = (tid & 31)*4;   // copy-thread mapping
  u64 h0v = 0;
  if (!isFirst){
    const u16* src = hstate + dir*32768 + (slice*16 + cr)*256 + hb*128 + cc4;
    h0v = *(const u64*)src;
  }
  *(u64*)&h_buf[0][cr][cc4] = h0v;
  float c[4], hacc[4] = {0,0,0,0}, cacc[4] = {0,0,0,0};
  {
    const long cb = ((long)(dir*16 + slice*2 + hb)*512 + tid)*4;
    #pragma unroll
    for (int r=0;r<4;r++) c[r] = isFirst ? 0.f : cstate[cb + r];
  }
  float wreg[8];
  #pragma unroll
  for (int i=0;i<8;i++) wreg[i] = wtg[i];

  u16*       myx   = hx + (long)(p*2 + hb)*2*2048;
  const u16* peerx = hx + (long)(p*2 + (1-hb))*2*2048;

  // prologue publish: h_0 into slot 0 with parity 0 (clear LSBs); no drain
  __hip_atomic_store((u64*)(myx + cr*128 + cc4), h0v & ~MRK,
                     __ATOMIC_RELAXED, __HIP_MEMORY_SCOPE_AGENT);
  __syncthreads();   // h_buf[0] visible to all waves

  // scatter-publish base (compute mapping): col = w*16+lr, rows lg*4+r
  const int pubCol = w*16 + lr;

  // packed pre base for this (slice,hb,w,lane): 32B contiguous per step
  const u16* preT = pre + (((long)slice*2 + hb)*8 + w)*1024 + (long)l*16;
  s16x8_t pfA = *(const s16x8_t*)(preT);
  s16x8_t pfB = *(const s16x8_t*)(preT + 8);

  for (int t = 0; t < CT; t++){
    const u64 exp2 = ((t>>1)&1) ? MRK : 0ull;
    const u16* pb = peerx + (long)(t&1)*2048 + lr*128 + lg*8;

    // ---- issue peer batch load EARLY (overlaps pre-prefetch + own-MFMA);
    //      single asm block: 4 loads + one wait, one LLC round trip.
    Q8 z0, z1, z2, z3;
    asm volatile(
      "global_load_dwordx4 %0, %4, off sc0 sc1\n\t"
      "global_load_dwordx4 %1, %4, off offset:64 sc0 sc1\n\t"
      "global_load_dwordx4 %2, %4, off offset:128 sc0 sc1\n\t"
      "global_load_dwordx4 %3, %4, off offset:192 sc0 sc1"
      : "=&v"(z0.s), "=&v"(z1.s), "=&v"(z2.s), "=&v"(z3.s)
      : "v"(pb) : "memory");

    // acc init from packed pre (bf16 -> f32)
    f32x4_t acc[4];
    #pragma unroll
    for (int r=0; r<4; r++){
      acc[0][r] = bf2f((u16)pfA[r]);
      acc[1][r] = bf2f((u16)pfA[4+r]);
      acc[2][r] = bf2f((u16)pfB[r]);
      acc[3][r] = bf2f((u16)pfB[4+r]);
    }
    if (t + 1 < CT){
      const u16* pp = preT + (long)(t+1)*131072;
      pfA = *(const s16x8_t*)(pp);
      pfB = *(const s16x8_t*)(pp + 8);
    }

    // ---- own-half K MFMAs (h_own from LDS) — independent of peer data
    {
      V8 af[4];
      const u16* hb0 = &h_buf[t&1][lr][lg*8];
      #pragma unroll
      for (int j=0;j<4;j++)
        af[j].s = *(const s16x8_t*)(hb0 + j*32);
      #pragma unroll
      for (int g=0;g<4;g++)
        #pragma unroll
        for (int j=0;j<4;j++)
          acc[g] = __builtin_amdgcn_mfma_f32_16x16x32_bf16(
              af[j].b, bwOwn[g][j].b, acc[g], 0,0,0);
    }

    // ---- wait for the batch, then validate markers; retry = full re-batch
    asm volatile("s_waitcnt vmcnt(0)" ::: "memory");
    __builtin_amdgcn_sched_barrier(0);
    {
      int tries = 0;
      while (true){
        int ok = ((z0.q[0] & MRK) == exp2) & ((z0.q[1] & MRK) == exp2)
               & ((z1.q[0] & MRK) == exp2) & ((z1.q[1] & MRK) == exp2)
               & ((z2.q[0] & MRK) == exp2) & ((z2.q[1] & MRK) == exp2)
               & ((z3.q[0] & MRK) == exp2) & ((z3.q[1] & MRK) == exp2);
        if (__all(ok)) break;
        if (++tries > (1<<16)) break;    // fail loud (wrong result), not hang
        __builtin_amdgcn_s_sleep(1);
        asm volatile(
          "global_load_dwordx4 %0, %4, off sc0 sc1\n\t"
          "global_load_dwordx4 %1, %4, off offset:64 sc0 sc1\n\t"
          "global_load_dwordx4 %2, %4, off offset:128 sc0 sc1\n\t"
          "global_load_dwordx4 %3, %4, off offset:192 sc0 sc1\n\t"
          "s_waitcnt vmcnt(0)"
          : "=&v"(z0.s), "=&v"(z1.s), "=&v"(z2.s), "=&v"(z3.s)
          : "v"(pb) : "memory");
        __builtin_amdgcn_sched_barrier(0);
      }
    }
    // ---- peer-half K MFMAs
    {
      V8 pafr[4];
      pafr[0].s = z0.s; pafr[1].s = z1.s; pafr[2].s = z2.s; pafr[3].s = z3.s;
      #pragma unroll
      for (int g=0;g<4;g++)
        #pragma unroll
        for (int j=0;j<4;j++)
          acc[g] = __builtin_amdgcn_mfma_f32_16x16x32_bf16(
              pafr[j].b, bwPeer[g][j].b, acc[g], 0,0,0);
    }

    // ---- gates + state update (lane-local: 4 rows of one h-col)
    const float wtv = wreg[t & 7];
    const bool last = (t & 7) == 7;
    float hout[4];
    #pragma unroll
    for (int r=0;r<4;r++){
      float iv = sigmoidf_(acc[0][r]);
      float fv = sigmoidf_(acc[1][r]);
      float gv = tanhf_  (acc[2][r]);
      float ov = sigmoidf_(acc[3][r]);
      float cn = fv*c[r] + iv*gv;
      float hh = ov*tanhf_(cn);
      float ha = hacc[r] + wtv*hh;
      float ca = cacc[r] + wtv*cn;
      hout[r] = last ? ha : hh;
      c[r]    = last ? ca : cn;
      hacc[r] = last ? 0.f : ha;
      cacc[r] = last ? 0.f : ca;
    }

    // ---- EARLY publish: 4 scattered marked 2B stores straight from regs
    u16 hb16[4];
    #pragma unroll
    for (int r=0;r<4;r++) hb16[r] = f2bf(hout[r]);
    if (t < CT - 1){
      const u16 pm1 = (u16)((((t+1)>>1)&1));
      u16* dst = myx + (long)((t+1)&1)*2048 + pubCol;
      #pragma unroll
      for (int r=0;r<4;r++){
        u16 v = (u16)((hb16[r] & 0xFFFEu) | pm1);
        __hip_atomic_store(dst + (lg*4+r)*128, v,
                           __ATOMIC_RELAXED, __HIP_MEMORY_SCOPE_AGENT);
      }
    }

    // ---- own h_{t+1} into the other LDS buffer; single barrier per step
    #pragma unroll
    for (int r=0;r<4;r++)
      h_buf[(t+1)&1][lg*4 + r][pubCol] = hb16[r];
    __syncthreads();

    // out write (coalesced u64, fire-and-forget, off critical path)
    {
      u16x4_t v = *(const u16x4_t*)&h_buf[(t+1)&1][cr][cc4];
      const long orow = (long)(outBase + t)*128 + slice*16 + cr;
      *(u16x4_t*)(out + orow*512 + dir*256 + hb*128 + cc4) = v;
    }
  }

  // ---- state save (CT even -> h_CT in buf[0])
  {
    u16* dst = hstate + dir*32768 + (slice*16 + cr)*256 + hb*128 + cc4;
    *(u16x4_t*)dst = *(const u16x4_t*)&h_buf[CT&1][cr][cc4];
  }
  {
    const long cb = ((long)(dir*16 + slice*2 + hb)*512 + tid)*4;
    #pragma unroll
    for (int r=0;r<4;r++) cstate[cb + r] = c[r];
  }
}

// ---------------------------------------------------------------- output proj
__global__ __launch_bounds__(256) void kout(const u16* __restrict__ Ab,
    const u16* __restrict__ Wo, const float* __restrict__ bo,
    float* __restrict__ op, int chunkRow0)
{
  __shared__ u16 Ws[4096];
  __shared__ u16 Rs[32*520];
  const int tid = threadIdx.x;
  {
    int f = tid*8;
    *(s16x8_t*)&Ws[f] = *(const s16x8_t*)(Wo + f);
    *(s16x8_t*)&Ws[f+2048] = *(const s16x8_t*)(Wo + f + 2048);
  }
  const long row0 = (long)blockIdx.x*32;
  #pragma unroll
  for (int i=0;i<8;i++){
    int f = tid*8 + i*2048;
    int rr = f >> 9, cc = f & 511;
    *(s16x8_t*)&Rs[rr*520 + cc] = *(const s16x8_t*)(Ab + (row0+rr)*512 + cc);
  }
  __syncthreads();
  const int rr = tid >> 3, d = tid & 7;
  float s = bo[d];
  for (int k=0;k<512;k+=8){
    s16x8_t a = *(const s16x8_t*)&Rs[rr*520 + k];
    s16x8_t wv = *(const s16x8_t*)&Ws[d*512 + k];
    #pragma unroll
    for (int e=0;e<8;e++)
      s += bf2f((u16)a[e]) * bf2f((u16)wv[e]);
  }
  const long grow = chunkRow0 + row0 + rr;
  const int tt = (int)(grow >> 7), b2 = (int)(grow & 127);
  op[((long)b2*1024 + tt)*8 + d] = s;
}

// ---------------------------------------------------------------- log_softmax over t (dim=1)
__global__ __launch_bounds__(256) void lsm(float* __restrict__ io){
  const int b = blockIdx.x >> 3, d = blockIdx.x & 7;
  const int tid = threadIdx.x;
  __shared__ float red[4];
  float v[4];
  float mx = -3.4e38f;
  const long base = (long)b*1024*8 + d;
  #pragma unroll
  for (int i=0;i<4;i++){
    v[i] = io[base + (long)(tid + i*256)*8];
    mx = fmaxf(mx, v[i]);
  }
  #pragma unroll
  for (int off=32; off>=1; off>>=1) mx = fmaxf(mx, __shfl_down(mx, off, 64));
  if ((tid & 63) == 0) red[tid >> 6] = mx;
  __syncthreads();
  mx = fmaxf(fmaxf(red[0],red[1]), fmaxf(red[2],red[3]));
  __syncthreads();
  float s = 0.f;
  #pragma unroll
  for (int i=0;i<4;i++) s += __expf(v[i]-mx);
  #pragma unroll
  for (int off=32; off>=1; off>>=1) s += __shfl_down(s, off, 64);
  if ((tid & 63) == 0) red[tid >> 6] = s;
  __syncthreads();
  s = red[0]+red[1]+red[2]+red[3];
  float lse = mx + __logf(s);
  #pragma unroll
  for (int i=0;i<4;i++) io[base + (long)(tid + i*256)*8] = v[i] - lse;
}

// ---------------------------------------------------------------- launch
extern "C" void kernel_launch(void* const* d_in, const int* in_sizes, int n_in,
                              void* d_out, int out_size, void* d_ws, size_t ws_size,
                              hipStream_t stream){
  const float* x     = (const float*)d_in[0];
  const float* W_in  = (const float*)d_in[1];
  const float* b_in  = (const float*)d_in[2];
  const float* Wih1  = (const float*)d_in[3];
  const float* Whh1  = (const float*)d_in[4];
  const float* bih1  = (const float*)d_in[5];
  const float* bhh1  = (const float*)d_in[6];
  const float* Wih2  = (const float*)d_in[7];
  const float* Whh2  = (const float*)d_in[8];
  const float* bih2  = (const float*)d_in[9];
  const float* bhh2  = (const float*)d_in[10];
  const float* wt1   = (const float*)d_in[11];
  const float* wt2   = (const float*)d_in[12];
  const float* W_out = (const float*)d_in[13];
  const float* b_out = (const float*)d_in[14];

  auto rnd = [](size_t b){ return (b + 255) & ~(size_t)255; };

  const size_t ACT1B   = (size_t)TT*BB*512*2;       // 128 MB
  const size_t WIHB    = (size_t)GATES*INL*2;       // 1 MB
  const size_t WFRAGB  = (size_t)GATES*HIDN*2;      // 512 KB
  const size_t WINB    = (size_t)INL*DIN*2;
  const size_t WOUTB   = (size_t)DOUT*INL*2;
  const size_t HSTB    = (size_t)2*BB*HIDN*2;       // 128 KB
  const size_t CSTB    = (size_t)32*512*4*4;        // 256 KB
  const size_t HXB     = (size_t)32*2*2048*2;       // 256 KB (bf16 payload)

  const size_t fixedB = rnd(ACT1B) + 2*rnd(WIHB) + 2*rnd(WFRAGB) + rnd(WINB)
                      + rnd(WOUTB) + rnd(HSTB) + rnd(CSTB) + rnd(HXB);

  // pick largest chunk length whose budget fits ws_size (all cands ≡ 0 mod 4:
  // chunk-final publishes carry parity 1, so new-launch t=0/1 (expect 0) are
  // blocked by stale data — the marker ring is safe across launches)
  int CT = 8;
  const int cands[8] = {1024,512,256,128,64,32,16,8};
  for (int ci = 0; ci < 8; ci++){
    int cand = cands[ci];
    size_t need = fixedB + rnd((size_t)cand*BB*512*2) + 2*rnd((size_t)cand*BB*GATES*2);
    if (need <= ws_size){ CT = cand; break; }
  }
  const int nc = TT / CT;

  char* ws = (char*)d_ws;
  size_t off = 0;
  auto alloc = [&](size_t bytes) -> void* {
    void* p = ws + off;
    off += rnd(bytes);
    return p;
  };

  u16*   act1    = (u16*)alloc(ACT1B);
  u16*   Wihb0   = (u16*)alloc(WIHB);
  u16*   Wihb1   = (u16*)alloc(WIHB);
  u16*   wfrag0  = (u16*)alloc(WFRAGB);
  u16*   wfrag1  = (u16*)alloc(WFRAGB);
  u16*   Winb    = (u16*)alloc(WINB);
  u16*   Woutb   = (u16*)alloc(WOUTB);
  u16*   hstate  = (u16*)alloc(HSTB);
  float* cstate  = (float*)alloc(CSTB);
  u16*   hx      = (u16*)alloc(HXB);
  u16*   actchunk= (u16*)alloc((size_t)CT*BB*512*2);
  u16*   pre0    = (u16*)alloc((size_t)CT*BB*GATES*2);
  u16*   pre1    = (u16*)alloc((size_t)CT*BB*GATES*2);

  // invalidate exchange markers once per call: 0xFF -> every bf16 LSB = 1,
  // which never matches the parity-0 expectation of the first reads
  hipMemsetAsync(hx, 0xFF, HXB, stream);

  // weight converts + packs
  cvt_f32_bf16<<<(GATES*INL/4 + 255)/256, 256, 0, stream>>>(Wih1, Wihb0, GATES*INL/4);
  cvt_f32_bf16<<<(GATES*INL/4 + 255)/256, 256, 0, stream>>>(Wih2, Wihb1, GATES*INL/4);
  cvt_f32_bf16<<<(INL*DIN/4 + 255)/256, 256, 0, stream>>>(W_in, Winb, INL*DIN/4);
  cvt_f32_bf16<<<(DOUT*INL/4 + 255)/256, 256, 0, stream>>>(W_out, Woutb, DOUT*INL/4);
  pack_whh<<<128, 256, 0, stream>>>(Whh1, wfrag0);
  pack_whh<<<128, 256, 0, stream>>>(Whh2, wfrag1);

  // ---- layer 1 (input proj recomputed per chunk from x)
  for (int c2 = 0; c2 < nc; c2++){
    gemm_tile<1,0><<<dim3(4, CT), 256, 0, stream>>>(x, Winb, actchunk,
        b_in, nullptr, DIN, 512, c2*CT, 1);
    gemm_tile<0,1><<<dim3(8, CT), 256, 0, stream>>>(actchunk, Wihb0, pre0,
        bih1, bhh1, INL, GATES, 0, 1);
    gemm_tile<1,0><<<dim3(4, CT), 256, 0, stream>>>(x, Winb, actchunk,
        b_in, nullptr, DIN, 512, 1023 - c2*CT, -1);
    gemm_tile<0,1><<<dim3(8, CT), 256, 0, stream>>>(actchunk, Wihb1, pre1,
        bih2, bhh2, INL, GATES, 0, 1);
    lstm_rec11<<<dim3(32), 512, 0, stream>>>(pre0, pre1, wfrag0, wfrag1,
        wt1, wt2, act1, c2*CT, CT, c2 == 0, hstate, cstate, hx);
  }

  // ---- layer 2 (reads act1; output chunk -> fused small out-proj)
  for (int c2 = 0; c2 < nc; c2++){
    gemm_tile<0,1><<<dim3(8, CT), 256, 0, stream>>>(act1, Wihb0, pre0,
        bih1, bhh1, INL, GATES, c2*CT, 1);
    gemm_tile<0,1><<<dim3(8, CT), 256, 0, stream>>>(act1, Wihb1, pre1,
        bih2, bhh2, INL, GATES, 1023 - c2*CT, -1);
    lstm_rec11<<<dim3(32), 512, 0, stream>>>(pre0, pre1, wfrag0, wfrag1,
        wt1, wt2, actchunk, 0, CT, c2 == 0, hstate, cstate, hx);
    kout<<<CT*4, 256, 0, stream>>>(actchunk, Woutb, b_out,
        (float*)d_out, c2*CT*128);
  }

  lsm<<<BB*DOUT, 256, 0, stream>>>((float*)d_out);
}

// Round 13
// 6944.268 us; speedup vs baseline: 3.1808x; 1.1356x over previous
//
#include <hip/hip_runtime.h>
#include <stdint.h>
#include <stddef.h>

// Problem constants (from reference)
#define HIDN 256
#define GATES 1024
#define INL 512
#define BB 128
#define TT 1024
#define TSS 8
#define DIN 128
#define DOUT 8

typedef unsigned short u16;
typedef unsigned int u32;
typedef unsigned long long u64;
typedef __bf16 bf16x8_t __attribute__((ext_vector_type(8)));
typedef float f32x4_t __attribute__((ext_vector_type(4)));
typedef short s16x8_t __attribute__((ext_vector_type(8)));
typedef u16 u16x4_t __attribute__((ext_vector_type(4)));

union V8 { s16x8_t s; bf16x8_t b; };
union Q8 { s16x8_t s; u64 q[2]; };

#define MRK 0x0001000100010001ull   // bf16-LSB marker bits in a u64 (4 bf16)

__device__ __forceinline__ u16 f2bf(float f){
  unsigned u = __builtin_bit_cast(unsigned, f);
  u += 0x7FFFu + ((u >> 16) & 1u);
  return (u16)(u >> 16);
}
__device__ __forceinline__ float bf2f(u16 h){
  unsigned u = ((unsigned)h) << 16;
  return __builtin_bit_cast(float, u);
}
__device__ __forceinline__ float sigmoidf_(float x){ return 1.f/(1.f + __expf(-x)); }
__device__ __forceinline__ float tanhf_(float x){
  float ax = fabsf(x);
  float e = __expf(-2.f*ax);          // no overflow for any x
  float t = (1.f - e)/(1.f + e);
  return x < 0.f ? -t : t;
}

// ---------------------------------------------------------------- converts
__global__ __launch_bounds__(256) void cvt_f32_bf16(const float* __restrict__ in,
                                                    u16* __restrict__ out, int n4){
  int i = blockIdx.x*256 + threadIdx.x;
  if (i < n4){
    float4 f = ((const float4*)in)[i];
    u16x4_t u;
    u[0] = f2bf(f.x); u[1] = f2bf(f.y); u[2] = f2bf(f.z); u[3] = f2bf(f.w);
    ((u16x4_t*)out)[i] = u;
  }
}

// Pack Whh [1024][256] f32 into MFMA B-fragment order (bf16):
// frag (nt,kt): lane l, elem e -> Whh[nt*16 + (l&15)][kt*32 + (l>>4)*8 + e]
__global__ __launch_bounds__(256) void pack_whh(const float* __restrict__ Whh,
                                                u16* __restrict__ wf){
  int idx = blockIdx.x*256 + threadIdx.x;     // 32768 total
  int l  = idx & 63;
  int kt = (idx >> 6) & 7;
  int nt = idx >> 9;
  int j = nt*16 + (l & 15);
  int k = kt*32 + (l >> 4)*8;
  const float* src = Whh + (long)j*HIDN + k;
  s16x8_t pk;
  #pragma unroll
  for (int e=0;e<8;e++) pk[e] = (short)f2bf(src[e]);
  *(s16x8_t*)(wf + (long)idx*8) = pk;
}

// ---------------------------------------------------------------- GEMM
// C[M][N] = A[M][K] @ W[N][K]^T (+bias1+bias2), fp32 accum, bf16 out.
// global_load_lds width-16 staging, LINEAR LDS [128][32] (m97 structure).
// XA=0: A bf16, source row = (srcT0 + sdir*by)*128 + row (row stride K)
// XA=1: A = x f32 [B=128][T=1024][128]; source row = row*1024 + (srcT0+sdir*by)
// OM=0: plain rows C[(by*128+row)*N + col]
// OM=1: packed for lstm_rec12: (by*8+slice)*16+ct)*1024 + l*16 + g*4+r
//       (identical bytes to the old (slice*2+hb)*8+w form: ct = hb*8+w)
template<int XA, int OM>
__global__ __launch_bounds__(256, 2) void gemm_tile(
    const void* __restrict__ Av, const u16* __restrict__ W,
    u16* __restrict__ C,
    const float* __restrict__ bias1, const float* __restrict__ bias2,
    int K, int N, int srcT0, int sdir)
{
  __shared__ u16 As[128*32];
  __shared__ u16 Ws[128*32];
  const int tid = threadIdx.x;
  const int l = tid & 63, wid = tid >> 6;
  const int lr = l & 15, lg = l >> 4;
  const int wm = (wid >> 1)*64, wn = (wid & 1)*64;
  const int by = blockIdx.y, bx = blockIdx.x;
  const int n0 = bx*128;
  const int m0 = by*128;

  f32x4_t acc[4][4];
  #pragma unroll
  for (int i=0;i<4;i++)
    #pragma unroll
    for (int j=0;j<4;j++){ f32x4_t z = {0.f,0.f,0.f,0.f}; acc[i][j] = z; }

  const long abase = (long)(srcT0 + sdir*by)*128;  // XA==0 source-row base
  const int srow = l >> 2;                         // lane row within 16-row group
  const int scol = (l & 3)*8;                      // lane col (u16)

  for (int k0 = 0; k0 < K; k0 += 32){
    __syncthreads();
    if (XA == 0){
      const u16* A = (const u16*)Av;
      #pragma unroll
      for (int c=0;c<2;c++){
        const int rb = wid*16 + c*64;              // wave-uniform row base
        __builtin_amdgcn_global_load_lds(
          (const __attribute__((address_space(1))) void*)
              (A + (abase + rb + srow)*(long)K + k0 + scol),
          (__attribute__((address_space(3))) void*)(&As[rb*32]),
          16, 0, 0);
      }
    } else {
      const float* A = (const float*)Av;
      const int xT = srcT0 + sdir*by;
      const int r0 = tid >> 2, c0 = (tid & 3)*8;
      #pragma unroll
      for (int c=0;c<2;c++){
        int row = r0 + c*64;
        const float* src = A + ((long)row*1024 + xT)*128 + k0 + c0;
        float4 f0 = *(const float4*)src;
        float4 f1 = *(const float4*)(src + 4);
        s16x8_t pk;
        pk[0]=(short)f2bf(f0.x); pk[1]=(short)f2bf(f0.y);
        pk[2]=(short)f2bf(f0.z); pk[3]=(short)f2bf(f0.w);
        pk[4]=(short)f2bf(f1.x); pk[5]=(short)f2bf(f1.y);
        pk[6]=(short)f2bf(f1.z); pk[7]=(short)f2bf(f1.w);
        *(s16x8_t*)(&As[row*32 + c0]) = pk;
      }
    }
    #pragma unroll
    for (int c=0;c<2;c++){
      const int rb = wid*16 + c*64;
      __builtin_amdgcn_global_load_lds(
        (const __attribute__((address_space(1))) void*)
            (W + (long)(n0 + rb + srow)*K + k0 + scol),
        (__attribute__((address_space(3))) void*)(&Ws[rb*32]),
        16, 0, 0);
    }
    __syncthreads();   // drains vmcnt (gload_lds) + lgkmcnt (XA=1 ds_write)

    V8 af[4], bfr[4];
    #pragma unroll
    for (int i=0;i<4;i++)
      af[i].s = *(const s16x8_t*)(&As[(wm + i*16 + lr)*32 + lg*8]);
    #pragma unroll
    for (int j=0;j<4;j++)
      bfr[j].s = *(const s16x8_t*)(&Ws[(wn + j*16 + lr)*32 + lg*8]);
    #pragma unroll
    for (int i=0;i<4;i++)
      #pragma unroll
      for (int j=0;j<4;j++)
        acc[i][j] = __builtin_amdgcn_mfma_f32_16x16x32_bf16(af[i].b, bfr[j].b, acc[i][j], 0,0,0);
  }

  #pragma unroll
  for (int i=0;i<4;i++){
    #pragma unroll
    for (int j=0;j<4;j++){
      if (OM == 0){
        int col = n0 + wn + j*16 + lr;
        float bb = bias1 ? bias1[col] : 0.f;
        if (bias2) bb += bias2[col];
        #pragma unroll
        for (int r=0;r<4;r++){
          int mrow = m0 + wm + i*16 + lg*4 + r;
          C[(long)mrow*N + col] = f2bf(acc[i][j][r] + bb);
        }
      } else {
        int colb = n0 + wn + j*16;          // multiple of 16
        int col = colb + lr;
        int g   = colb >> 8;
        int ct2 = (colb >> 4) & 15;         // col-tile within gate
        int slice = (wm >> 4) + i;
        float bb = bias1[col] + bias2[col];
        u16x4_t v;
        #pragma unroll
        for (int r=0;r<4;r++) v[r] = f2bf(acc[i][j][r] + bb);
        long dst = (((long)by*8 + slice)*16 + ct2)*1024
                 + (long)l*16 + g*4;
        *(u16x4_t*)(C + dst) = v;
      }
    }
  }
}

// ---------------------------------------------------------------- recurrence
// r13: 256 INDEPENDENT single-wave blocks: bid = (dir*8+slice)*16 + ct.
// Wave owns h-cols [ct*16,(ct+1)*16) x batch rows [slice*16,+16); weights
// 4 gates x 8 kt = 128 VGPR register-resident. NO LDS, NO __syncthreads:
// all of h_t is read from the marked LLC buffer (bf16-LSB step-parity,
// r8-proven); publish = 4 scattered marked 2B stores (r11-proven); read =
// one asm batch of 8x global_load_dwordx4 sc0 sc1 (r12-proven).
// Rationale: r12's rec was VALU/trans-bound on 32 CUs (GPU-wide VALUBusy
// 6.7% at 12.5% CU usage); 1 wave/SIMD removes trans-unit sharing.
__global__ __launch_bounds__(64, 2) void lstm_rec12(
    const u16* __restrict__ pre0, const u16* __restrict__ pre1,
    const u16* __restrict__ wf0, const u16* __restrict__ wf1,
    const float* __restrict__ wt0, const float* __restrict__ wt1,
    u16* __restrict__ out,      // rows (outBase+t)*128+b, 512 cols
    int outBase, int CT, int isFirst,
    u16* __restrict__ hstate,   // [dir][128][256] bf16
    float* __restrict__ cstate, // [(p*16+ct)*64 + l][4] f32
    u16* __restrict__ hxx)      // [p][slot(2)][16][256] bf16 (marked)
{
  const int bid = blockIdx.x;
  const int ct  = bid & 15;
  const int p   = bid >> 4;           // dir*8 + slice
  const int dir = p >> 3, slice = p & 7;
  const int l = threadIdx.x & 63;
  const int lr = l & 15, lg = l >> 4;

  const u16*   wf  = dir ? wf1 : wf0;
  const float* wtg = dir ? wt1 : wt0;
  const u16*   pre = dir ? pre1 : pre0;

  // ---- weights resident: 4 gates x 8 kt = 32 fragments = 128 regs/lane.
  V8 bw[4][8];
  #pragma unroll
  for (int g=0; g<4; g++){
    const int nt = g*16 + ct;
    const u16* base = wf + ((long)nt*8*64 + l)*8;
    #pragma unroll
    for (int kt=0; kt<8; kt++)
      bw[g][kt].s = *(const s16x8_t*)(base + (long)kt*64*8);
  }

  float c[4], hacc[4] = {0,0,0,0}, cacc[4] = {0,0,0,0};
  {
    const long cb = (((long)p*16 + ct)*64 + l)*4;
    #pragma unroll
    for (int r=0;r<4;r++) c[r] = isFirst ? 0.f : cstate[cb + r];
  }
  float wreg[8];
  #pragma unroll
  for (int i=0;i<8;i++) wreg[i] = wtg[i];

  u16* hgrp = hxx + (long)p*2*4096;   // [slot][16][256]

  // prologue: publish own h_0 stripe with parity 0 (slot 0)
  #pragma unroll
  for (int r=0;r<4;r++){
    const int row = lg*4 + r, col = ct*16 + lr;
    u16 h0 = 0;
    if (!isFirst) h0 = hstate[dir*32768 + (slice*16 + row)*256 + col];
    __hip_atomic_store(hgrp + row*256 + col, (u16)(h0 & 0xFFFEu),
                       __ATOMIC_RELAXED, __HIP_MEMORY_SCOPE_AGENT);
  }

  // packed pre base for this (slice,ct,lane): 32B contiguous per step
  const u16* preT = pre + ((long)slice*16 + ct)*1024 + (long)l*16;
  s16x8_t pfA = *(const s16x8_t*)(preT);
  s16x8_t pfB = *(const s16x8_t*)(preT + 8);

  for (int t = 0; t < CT; t++){
    const u64 exp2 = ((t>>1)&1) ? MRK : 0ull;
    // lane reads row lr of h_t: 8 x 16B at stride 64B
    const u16* pb = hgrp + (t&1)*4096 + lr*256 + lg*8;

    // ---- issue the full h_t read EARLY (one batch, one round trip)
    Q8 z0, z1, z2, z3, z4, z5, z6, z7;
    asm volatile(
      "global_load_dwordx4 %0, %8, off sc0 sc1\n\t"
      "global_load_dwordx4 %1, %8, off offset:64 sc0 sc1\n\t"
      "global_load_dwordx4 %2, %8, off offset:128 sc0 sc1\n\t"
      "global_load_dwordx4 %3, %8, off offset:192 sc0 sc1\n\t"
      "global_load_dwordx4 %4, %8, off offset:256 sc0 sc1\n\t"
      "global_load_dwordx4 %5, %8, off offset:320 sc0 sc1\n\t"
      "global_load_dwordx4 %6, %8, off offset:384 sc0 sc1\n\t"
      "global_load_dwordx4 %7, %8, off offset:448 sc0 sc1"
      : "=&v"(z0.s), "=&v"(z1.s), "=&v"(z2.s), "=&v"(z3.s),
        "=&v"(z4.s), "=&v"(z5.s), "=&v"(z6.s), "=&v"(z7.s)
      : "v"(pb) : "memory");

    // acc init from packed pre (bf16 -> f32) — overlaps load latency
    f32x4_t acc[4];
    #pragma unroll
    for (int r=0; r<4; r++){
      acc[0][r] = bf2f((u16)pfA[r]);
      acc[1][r] = bf2f((u16)pfA[4+r]);
      acc[2][r] = bf2f((u16)pfB[r]);
      acc[3][r] = bf2f((u16)pfB[4+r]);
    }
    if (t + 1 < CT){
      const u16* pp = preT + (long)(t+1)*131072;
      pfA = *(const s16x8_t*)(pp);
      pfB = *(const s16x8_t*)(pp + 8);
    }

    // ---- wait + validate markers; retry = full re-batch
    asm volatile("s_waitcnt vmcnt(0)" ::: "memory");
    __builtin_amdgcn_sched_barrier(0);
    {
      int tries = 0;
      while (true){
        int ok = ((z0.q[0] & MRK) == exp2) & ((z0.q[1] & MRK) == exp2)
               & ((z1.q[0] & MRK) == exp2) & ((z1.q[1] & MRK) == exp2)
               & ((z2.q[0] & MRK) == exp2) & ((z2.q[1] & MRK) == exp2)
               & ((z3.q[0] & MRK) == exp2) & ((z3.q[1] & MRK) == exp2)
               & ((z4.q[0] & MRK) == exp2) & ((z4.q[1] & MRK) == exp2)
               & ((z5.q[0] & MRK) == exp2) & ((z5.q[1] & MRK) == exp2)
               & ((z6.q[0] & MRK) == exp2) & ((z6.q[1] & MRK) == exp2)
               & ((z7.q[0] & MRK) == exp2) & ((z7.q[1] & MRK) == exp2);
        if (__all(ok)) break;
        if (++tries > (1<<16)) break;    // fail loud (wrong result), not hang
        __builtin_amdgcn_s_sleep(1);
        asm volatile(
          "global_load_dwordx4 %0, %8, off sc0 sc1\n\t"
          "global_load_dwordx4 %1, %8, off offset:64 sc0 sc1\n\t"
          "global_load_dwordx4 %2, %8, off offset:128 sc0 sc1\n\t"
          "global_load_dwordx4 %3, %8, off offset:192 sc0 sc1\n\t"
          "global_load_dwordx4 %4, %8, off offset:256 sc0 sc1\n\t"
          "global_load_dwordx4 %5, %8, off offset:320 sc0 sc1\n\t"
          "global_load_dwordx4 %6, %8, off offset:384 sc0 sc1\n\t"
          "global_load_dwordx4 %7, %8, off offset:448 sc0 sc1\n\t"
          "s_waitcnt vmcnt(0)"
          : "=&v"(z0.s), "=&v"(z1.s), "=&v"(z2.s), "=&v"(z3.s),
            "=&v"(z4.s), "=&v"(z5.s), "=&v"(z6.s), "=&v"(z7.s)
          : "v"(pb) : "memory");
        __builtin_amdgcn_sched_barrier(0);
      }
    }

    // ---- full-K MFMAs: 8 kt x 4 gates (4 independent chains)
    {
      V8 a0, a1, a2, a3, a4, a5, a6, a7;
      a0.s = z0.s; a1.s = z1.s; a2.s = z2.s; a3.s = z3.s;
      a4.s = z4.s; a5.s = z5.s; a6.s = z6.s; a7.s = z7.s;
      #pragma unroll
      for (int g=0; g<4; g++){
        acc[g] = __builtin_amdgcn_mfma_f32_16x16x32_bf16(a0.b, bw[g][0].b, acc[g], 0,0,0);
        acc[g] = __builtin_amdgcn_mfma_f32_16x16x32_bf16(a1.b, bw[g][1].b, acc[g], 0,0,0);
        acc[g] = __builtin_amdgcn_mfma_f32_16x16x32_bf16(a2.b, bw[g][2].b, acc[g], 0,0,0);
        acc[g] = __builtin_amdgcn_mfma_f32_16x16x32_bf16(a3.b, bw[g][3].b, acc[g], 0,0,0);
        acc[g] = __builtin_amdgcn_mfma_f32_16x16x32_bf16(a4.b, bw[g][4].b, acc[g], 0,0,0);
        acc[g] = __builtin_amdgcn_mfma_f32_16x16x32_bf16(a5.b, bw[g][5].b, acc[g], 0,0,0);
        acc[g] = __builtin_amdgcn_mfma_f32_16x16x32_bf16(a6.b, bw[g][6].b, acc[g], 0,0,0);
        acc[g] = __builtin_amdgcn_mfma_f32_16x16x32_bf16(a7.b, bw[g][7].b, acc[g], 0,0,0);
      }
    }

    // ---- gates + state update (lane-local: 4 rows of one h-col)
    const float wtv = wreg[t & 7];
    const bool last = (t & 7) == 7;
    float hout[4];
    #pragma unroll
    for (int r=0;r<4;r++){
      float iv = sigmoidf_(acc[0][r]);
      float fv = sigmoidf_(acc[1][r]);
      float gv = tanhf_  (acc[2][r]);
      float ov = sigmoidf_(acc[3][r]);
      float cn = fv*c[r] + iv*gv;
      float hh = ov*tanhf_(cn);
      float ha = hacc[r] + wtv*hh;
      float ca = cacc[r] + wtv*cn;
      hout[r] = last ? ha : hh;
      c[r]    = last ? ca : cn;
      hacc[r] = last ? 0.f : ha;
      cacc[r] = last ? 0.f : ca;
    }

    // ---- publish h_{t+1}: 4 scattered marked 2B stores (fire-and-forget)
    u16 hb16[4];
    #pragma unroll
    for (int r=0;r<4;r++) hb16[r] = f2bf(hout[r]);
    if (t < CT - 1){
      const u16 pm1 = (u16)((((t+1)>>1)&1));
      u16* dst = hgrp + ((t+1)&1)*4096 + ct*16 + lr;
      #pragma unroll
      for (int r=0;r<4;r++){
        u16 v = (u16)((hb16[r] & 0xFFFEu) | pm1);
        __hip_atomic_store(dst + (lg*4+r)*256, v,
                           __ATOMIC_RELAXED, __HIP_MEMORY_SCOPE_AGENT);
      }
    }

    // ---- out write (clean values, fire-and-forget)
    {
      const long orow0 = (long)(outBase + t)*128 + slice*16;
      #pragma unroll
      for (int r=0;r<4;r++)
        out[(orow0 + lg*4 + r)*512 + dir*256 + ct*16 + lr] = hb16[r];
    }

    // ---- carry final h into hstate at the last step
    if (t == CT - 1){
      #pragma unroll
      for (int r=0;r<4;r++)
        hstate[dir*32768 + (slice*16 + lg*4 + r)*256 + ct*16 + lr] = hb16[r];
    }
  }

  // ---- c-state save
  {
    const long cb = (((long)p*16 + ct)*64 + l)*4;
    #pragma unroll
    for (int r=0;r<4;r++) cstate[cb + r] = c[r];
  }
}

// ---------------------------------------------------------------- output proj
__global__ __launch_bounds__(256) void kout(const u16* __restrict__ Ab,
    const u16* __restrict__ Wo, const float* __restrict__ bo,
    float* __restrict__ op, int chunkRow0)
{
  __shared__ u16 Ws[4096];
  __shared__ u16 Rs[32*520];
  const int tid = threadIdx.x;
  {
    int f = tid*8;
    *(s16x8_t*)&Ws[f] = *(const s16x8_t*)(Wo + f);
    *(s16x8_t*)&Ws[f+2048] = *(const s16x8_t*)(Wo + f + 2048);
  }
  const long row0 = (long)blockIdx.x*32;
  #pragma unroll
  for (int i=0;i<8;i++){
    int f = tid*8 + i*2048;
    int rr = f >> 9, cc = f & 511;
    *(s16x8_t*)&Rs[rr*520 + cc] = *(const s16x8_t*)(Ab + (row0+rr)*512 + cc);
  }
  __syncthreads();
  const int rr = tid >> 3, d = tid & 7;
  float s = bo[d];
  for (int k=0;k<512;k+=8){
    s16x8_t a = *(const s16x8_t*)&Rs[rr*520 + k];
    s16x8_t wv = *(const s16x8_t*)&Ws[d*512 + k];
    #pragma unroll
    for (int e=0;e<8;e++)
      s += bf2f((u16)a[e]) * bf2f((u16)wv[e]);
  }
  const long grow = chunkRow0 + row0 + rr;
  const int tt = (int)(grow >> 7), b2 = (int)(grow & 127);
  op[((long)b2*1024 + tt)*8 + d] = s;
}

// ---------------------------------------------------------------- log_softmax over t (dim=1)
__global__ __launch_bounds__(256) void lsm(float* __restrict__ io){
  const int b = blockIdx.x >> 3, d = blockIdx.x & 7;
  const int tid = threadIdx.x;
  __shared__ float red[4];
  float v[4];
  float mx = -3.4e38f;
  const long base = (long)b*1024*8 + d;
  #pragma unroll
  for (int i=0;i<4;i++){
    v[i] = io[base + (long)(tid + i*256)*8];
    mx = fmaxf(mx, v[i]);
  }
  #pragma unroll
  for (int off=32; off>=1; off>>=1) mx = fmaxf(mx, __shfl_down(mx, off, 64));
  if ((tid & 63) == 0) red[tid >> 6] = mx;
  __syncthreads();
  mx = fmaxf(fmaxf(red[0],red[1]), fmaxf(red[2],red[3]));
  __syncthreads();
  float s = 0.f;
  #pragma unroll
  for (int i=0;i<4;i++) s += __expf(v[i]-mx);
  #pragma unroll
  for (int off=32; off>=1; off>>=1) s += __shfl_down(s, off, 64);
  if ((tid & 63) == 0) red[tid >> 6] = s;
  __syncthreads();
  s = red[0]+red[1]+red[2]+red[3];
  float lse = mx + __logf(s);
  #pragma unroll
  for (int i=0;i<4;i++) io[base + (long)(tid + i*256)*8] = v[i] - lse;
}

// ---------------------------------------------------------------- launch
extern "C" void kernel_launch(void* const* d_in, const int* in_sizes, int n_in,
                              void* d_out, int out_size, void* d_ws, size_t ws_size,
                              hipStream_t stream){
  const float* x     = (const float*)d_in[0];
  const float* W_in  = (const float*)d_in[1];
  const float* b_in  = (const float*)d_in[2];
  const float* Wih1  = (const float*)d_in[3];
  const float* Whh1  = (const float*)d_in[4];
  const float* bih1  = (const float*)d_in[5];
  const float* bhh1  = (const float*)d_in[6];
  const float* Wih2  = (const float*)d_in[7];
  const float* Whh2  = (const float*)d_in[8];
  const float* bih2  = (const float*)d_in[9];
  const float* bhh2  = (const float*)d_in[10];
  const float* wt1   = (const float*)d_in[11];
  const float* wt2   = (const float*)d_in[12];
  const float* W_out = (const float*)d_in[13];
  const float* b_out = (const float*)d_in[14];

  auto rnd = [](size_t b){ return (b + 255) & ~(size_t)255; };

  const size_t ACT1B   = (size_t)TT*BB*512*2;       // 128 MB
  const size_t WIHB    = (size_t)GATES*INL*2;       // 1 MB
  const size_t WFRAGB  = (size_t)GATES*HIDN*2;      // 512 KB
  const size_t WINB    = (size_t)INL*DIN*2;
  const size_t WOUTB   = (size_t)DOUT*INL*2;
  const size_t HSTB    = (size_t)2*BB*HIDN*2;       // 128 KB
  const size_t CSTB    = (size_t)16*16*64*4*4;      // 256 KB
  const size_t HXB     = (size_t)16*2*4096*2;       // 256 KB (bf16, marked)

  const size_t fixedB = rnd(ACT1B) + 2*rnd(WIHB) + 2*rnd(WFRAGB) + rnd(WINB)
                      + rnd(WOUTB) + rnd(HSTB) + rnd(CSTB) + rnd(HXB);

  // pick largest chunk length whose budget fits ws_size (cands ≡ 0 mod 4:
  // marker parity ring stays safe across launches)
  int CT = 8;
  const int cands[8] = {1024,512,256,128,64,32,16,8};
  for (int ci = 0; ci < 8; ci++){
    int cand = cands[ci];
    size_t need = fixedB + rnd((size_t)cand*BB*512*2) + 2*rnd((size_t)cand*BB*GATES*2);
    if (need <= ws_size){ CT = cand; break; }
  }
  const int nc = TT / CT;

  char* ws = (char*)d_ws;
  size_t off = 0;
  auto alloc = [&](size_t bytes) -> void* {
    void* p = ws + off;
    off += rnd(bytes);
    return p;
  };

  u16*   act1    = (u16*)alloc(ACT1B);
  u16*   Wihb0   = (u16*)alloc(WIHB);
  u16*   Wihb1   = (u16*)alloc(WIHB);
  u16*   wfrag0  = (u16*)alloc(WFRAGB);
  u16*   wfrag1  = (u16*)alloc(WFRAGB);
  u16*   Winb    = (u16*)alloc(WINB);
  u16*   Woutb   = (u16*)alloc(WOUTB);
  u16*   hstate  = (u16*)alloc(HSTB);
  float* cstate  = (float*)alloc(CSTB);
  u16*   hxx     = (u16*)alloc(HXB);
  u16*   actchunk= (u16*)alloc((size_t)CT*BB*512*2);
  u16*   pre0    = (u16*)alloc((size_t)CT*BB*GATES*2);
  u16*   pre1    = (u16*)alloc((size_t)CT*BB*GATES*2);

  // invalidate exchange markers once per call: 0xFF -> every bf16 LSB = 1,
  // which never matches the parity-0 expectation of the first reads
  hipMemsetAsync(hxx, 0xFF, HXB, stream);

  // weight converts + packs
  cvt_f32_bf16<<<(GATES*INL/4 + 255)/256, 256, 0, stream>>>(Wih1, Wihb0, GATES*INL/4);
  cvt_f32_bf16<<<(GATES*INL/4 + 255)/256, 256, 0, stream>>>(Wih2, Wihb1, GATES*INL/4);
  cvt_f32_bf16<<<(INL*DIN/4 + 255)/256, 256, 0, stream>>>(W_in, Winb, INL*DIN/4);
  cvt_f32_bf16<<<(DOUT*INL/4 + 255)/256, 256, 0, stream>>>(W_out, Woutb, DOUT*INL/4);
  pack_whh<<<128, 256, 0, stream>>>(Whh1, wfrag0);
  pack_whh<<<128, 256, 0, stream>>>(Whh2, wfrag1);

  // ---- layer 1 (input proj recomputed per chunk from x)
  for (int c2 = 0; c2 < nc; c2++){
    gemm_tile<1,0><<<dim3(4, CT), 256, 0, stream>>>(x, Winb, actchunk,
        b_in, nullptr, DIN, 512, c2*CT, 1);
    gemm_tile<0,1><<<dim3(8, CT), 256, 0, stream>>>(actchunk, Wihb0, pre0,
        bih1, bhh1, INL, GATES, 0, 1);
    gemm_tile<1,0><<<dim3(4, CT), 256, 0, stream>>>(x, Winb, actchunk,
        b_in, nullptr, DIN, 512, 1023 - c2*CT, -1);
    gemm_tile<0,1><<<dim3(8, CT), 256, 0, stream>>>(actchunk, Wihb1, pre1,
        bih2, bhh2, INL, GATES, 0, 1);
    lstm_rec12<<<dim3(256), 64, 0, stream>>>(pre0, pre1, wfrag0, wfrag1,
        wt1, wt2, act1, c2*CT, CT, c2 == 0, hstate, cstate, hxx);
  }

  // ---- layer 2 (reads act1; output chunk -> fused small out-proj)
  for (int c2 = 0; c2 < nc; c2++){
    gemm_tile<0,1><<<dim3(8, CT), 256, 0, stream>>>(act1, Wihb0, pre0,
        bih1, bhh1, INL, GATES, c2*CT, 1);
    gemm_tile<0,1><<<dim3(8, CT), 256, 0, stream>>>(act1, Wihb1, pre1,
        bih2, bhh2, INL, GATES, 1023 - c2*CT, -1);
    lstm_rec12<<<dim3(256), 64, 0, stream>>>(pre0, pre1, wfrag0, wfrag1,
        wt1, wt2, actchunk, 0, CT, c2 == 0, hstate, cstate, hxx);
    kout<<<CT*4, 256, 0, stream>>>(actchunk, Woutb, b_out,
        (float*)d_out, c2*CT*128);
  }

  lsm<<<BB*DOUT, 256, 0, stream>>>((float*)d_out);
}

// Round 14
// 6933.085 us; speedup vs baseline: 3.1860x; 1.0016x over previous
//
#include <hip/hip_runtime.h>
#include <stdint.h>
#include <stddef.h>

// Problem constants (from reference)
#define HIDN 256
#define GATES 1024
#define INL 512
#define BB 128
#define TT 1024
#define TSS 8
#define DIN 128
#define DOUT 8

typedef unsigned short u16;
typedef unsigned int u32;
typedef unsigned long long u64;
typedef __bf16 bf16x8_t __attribute__((ext_vector_type(8)));
typedef float f32x4_t __attribute__((ext_vector_type(4)));
typedef short s16x8_t __attribute__((ext_vector_type(8)));
typedef u16 u16x4_t __attribute__((ext_vector_type(4)));

union V8 { s16x8_t s; bf16x8_t b; };
union Q8 { s16x8_t s; u64 q[2]; };

#define MRK 0x0001000100010001ull   // bf16-LSB marker bits in a u64 (4 bf16)

__device__ __forceinline__ u16 f2bf(float f){
  unsigned u = __builtin_bit_cast(unsigned, f);
  u += 0x7FFFu + ((u >> 16) & 1u);
  return (u16)(u >> 16);
}
__device__ __forceinline__ float bf2f(u16 h){
  unsigned u = ((unsigned)h) << 16;
  return __builtin_bit_cast(float, u);
}
__device__ __forceinline__ float sigmoidf_(float x){ return 1.f/(1.f + __expf(-x)); }
__device__ __forceinline__ float tanhf_(float x){
  float ax = fabsf(x);
  float e = __expf(-2.f*ax);          // no overflow for any x
  float t = (1.f - e)/(1.f + e);
  return x < 0.f ? -t : t;
}

// ---------------------------------------------------------------- converts
__global__ __launch_bounds__(256) void cvt_f32_bf16(const float* __restrict__ in,
                                                    u16* __restrict__ out, int n4){
  int i = blockIdx.x*256 + threadIdx.x;
  if (i < n4){
    float4 f = ((const float4*)in)[i];
    u16x4_t u;
    u[0] = f2bf(f.x); u[1] = f2bf(f.y); u[2] = f2bf(f.z); u[3] = f2bf(f.w);
    ((u16x4_t*)out)[i] = u;
  }
}

// Pack Whh [1024][256] f32 into MFMA B-fragment order (bf16):
// frag (nt,kt): lane l, elem e -> Whh[nt*16 + (l&15)][kt*32 + (l>>4)*8 + e]
__global__ __launch_bounds__(256) void pack_whh(const float* __restrict__ Whh,
                                                u16* __restrict__ wf){
  int idx = blockIdx.x*256 + threadIdx.x;     // 32768 total
  int l  = idx & 63;
  int kt = (idx >> 6) & 7;
  int nt = idx >> 9;
  int j = nt*16 + (l & 15);
  int k = kt*32 + (l >> 4)*8;
  const float* src = Whh + (long)j*HIDN + k;
  s16x8_t pk;
  #pragma unroll
  for (int e=0;e<8;e++) pk[e] = (short)f2bf(src[e]);
  *(s16x8_t*)(wf + (long)idx*8) = pk;
}

// ---------------------------------------------------------------- GEMM
// C[M][N] = A[M][K] @ W[N][K]^T (+bias1+bias2), fp32 accum, bf16 out.
// global_load_lds width-16 staging, LINEAR LDS [128][32] (m97 structure).
// XA=0: A bf16, source row = (srcT0 + sdir*by)*128 + row (row stride K)
// XA=1: A = x f32 [B=128][T=1024][128]; source row = row*1024 + (srcT0+sdir*by)
// OM=0: plain rows C[(by*128+row)*N + col]
// OM=1: packed for lstm_rec12: (by*8+slice)*16+ct)*1024 + l*16 + g*4+r
//       (identical bytes to the old (slice*2+hb)*8+w form: ct = hb*8+w)
template<int XA, int OM>
__global__ __launch_bounds__(256, 2) void gemm_tile(
    const void* __restrict__ Av, const u16* __restrict__ W,
    u16* __restrict__ C,
    const float* __restrict__ bias1, const float* __restrict__ bias2,
    int K, int N, int srcT0, int sdir)
{
  __shared__ u16 As[128*32];
  __shared__ u16 Ws[128*32];
  const int tid = threadIdx.x;
  const int l = tid & 63, wid = tid >> 6;
  const int lr = l & 15, lg = l >> 4;
  const int wm = (wid >> 1)*64, wn = (wid & 1)*64;
  const int by = blockIdx.y, bx = blockIdx.x;
  const int n0 = bx*128;
  const int m0 = by*128;

  f32x4_t acc[4][4];
  #pragma unroll
  for (int i=0;i<4;i++)
    #pragma unroll
    for (int j=0;j<4;j++){ f32x4_t z = {0.f,0.f,0.f,0.f}; acc[i][j] = z; }

  const long abase = (long)(srcT0 + sdir*by)*128;  // XA==0 source-row base
  const int srow = l >> 2;                         // lane row within 16-row group
  const int scol = (l & 3)*8;                      // lane col (u16)

  for (int k0 = 0; k0 < K; k0 += 32){
    __syncthreads();
    if (XA == 0){
      const u16* A = (const u16*)Av;
      #pragma unroll
      for (int c=0;c<2;c++){
        const int rb = wid*16 + c*64;              // wave-uniform row base
        __builtin_amdgcn_global_load_lds(
          (const __attribute__((address_space(1))) void*)
              (A + (abase + rb + srow)*(long)K + k0 + scol),
          (__attribute__((address_space(3))) void*)(&As[rb*32]),
          16, 0, 0);
      }
    } else {
      const float* A = (const float*)Av;
      const int xT = srcT0 + sdir*by;
      const int r0 = tid >> 2, c0 = (tid & 3)*8;
      #pragma unroll
      for (int c=0;c<2;c++){
        int row = r0 + c*64;
        const float* src = A + ((long)row*1024 + xT)*128 + k0 + c0;
        float4 f0 = *(const float4*)src;
        float4 f1 = *(const float4*)(src + 4);
        s16x8_t pk;
        pk[0]=(short)f2bf(f0.x); pk[1]=(short)f2bf(f0.y);
        pk[2]=(short)f2bf(f0.z); pk[3]=(short)f2bf(f0.w);
        pk[4]=(short)f2bf(f1.x); pk[5]=(short)f2bf(f1.y);
        pk[6]=(short)f2bf(f1.z); pk[7]=(short)f2bf(f1.w);
        *(s16x8_t*)(&As[row*32 + c0]) = pk;
      }
    }
    #pragma unroll
    for (int c=0;c<2;c++){
      const int rb = wid*16 + c*64;
      __builtin_amdgcn_global_load_lds(
        (const __attribute__((address_space(1))) void*)
            (W + (long)(n0 + rb + srow)*K + k0 + scol),
        (__attribute__((address_space(3))) void*)(&Ws[rb*32]),
        16, 0, 0);
    }
    __syncthreads();   // drains vmcnt (gload_lds) + lgkmcnt (XA=1 ds_write)

    V8 af[4], bfr[4];
    #pragma unroll
    for (int i=0;i<4;i++)
      af[i].s = *(const s16x8_t*)(&As[(wm + i*16 + lr)*32 + lg*8]);
    #pragma unroll
    for (int j=0;j<4;j++)
      bfr[j].s = *(const s16x8_t*)(&Ws[(wn + j*16 + lr)*32 + lg*8]);
    #pragma unroll
    for (int i=0;i<4;i++)
      #pragma unroll
      for (int j=0;j<4;j++)
        acc[i][j] = __builtin_amdgcn_mfma_f32_16x16x32_bf16(af[i].b, bfr[j].b, acc[i][j], 0,0,0);
  }

  #pragma unroll
  for (int i=0;i<4;i++){
    #pragma unroll
    for (int j=0;j<4;j++){
      if (OM == 0){
        int col = n0 + wn + j*16 + lr;
        float bb = bias1 ? bias1[col] : 0.f;
        if (bias2) bb += bias2[col];
        #pragma unroll
        for (int r=0;r<4;r++){
          int mrow = m0 + wm + i*16 + lg*4 + r;
          C[(long)mrow*N + col] = f2bf(acc[i][j][r] + bb);
        }
      } else {
        int colb = n0 + wn + j*16;          // multiple of 16
        int col = colb + lr;
        int g   = colb >> 8;
        int ct2 = (colb >> 4) & 15;         // col-tile within gate
        int slice = (wm >> 4) + i;
        float bb = bias1[col] + bias2[col];
        u16x4_t v;
        #pragma unroll
        for (int r=0;r<4;r++) v[r] = f2bf(acc[i][j][r] + bb);
        long dst = (((long)by*8 + slice)*16 + ct2)*1024
                 + (long)l*16 + g*4;
        *(u16x4_t*)(C + dst) = v;
      }
    }
  }
}

// ---------------------------------------------------------------- recurrence
// r13: 256 INDEPENDENT single-wave blocks: bid = (dir*8+slice)*16 + ct.
// Wave owns h-cols [ct*16,(ct+1)*16) x batch rows [slice*16,+16); weights
// 4 gates x 8 kt = 128 VGPR register-resident. NO LDS, NO __syncthreads:
// all of h_t is read from the marked LLC buffer (bf16-LSB step-parity,
// r8-proven); publish = 4 scattered marked 2B stores (r11-proven); read =
// one asm batch of 8x global_load_dwordx4 sc0 sc1 (r12-proven).
// Rationale: r12's rec was VALU/trans-bound on 32 CUs (GPU-wide VALUBusy
// 6.7% at 12.5% CU usage); 1 wave/SIMD removes trans-unit sharing.
__global__ __launch_bounds__(64, 2) void lstm_rec12(
    const u16* __restrict__ pre0, const u16* __restrict__ pre1,
    const u16* __restrict__ wf0, const u16* __restrict__ wf1,
    const float* __restrict__ wt0, const float* __restrict__ wt1,
    u16* __restrict__ out,      // rows (outBase+t)*128+b, 512 cols
    int outBase, int CT, int isFirst,
    u16* __restrict__ hstate,   // [dir][128][256] bf16
    float* __restrict__ cstate, // [(p*16+ct)*64 + l][4] f32
    u16* __restrict__ hxx)      // [p][slot(2)][16][256] bf16 (marked)
{
  const int bid = blockIdx.x;
  const int ct  = bid & 15;
  const int p   = bid >> 4;           // dir*8 + slice
  const int dir = p >> 3, slice = p & 7;
  const int l = threadIdx.x & 63;
  const int lr = l & 15, lg = l >> 4;

  const u16*   wf  = dir ? wf1 : wf0;
  const float* wtg = dir ? wt1 : wt0;
  const u16*   pre = dir ? pre1 : pre0;

  // ---- weights resident: 4 gates x 8 kt = 32 fragments = 128 regs/lane.
  V8 bw[4][8];
  #pragma unroll
  for (int g=0; g<4; g++){
    const int nt = g*16 + ct;
    const u16* base = wf + ((long)nt*8*64 + l)*8;
    #pragma unroll
    for (int kt=0; kt<8; kt++)
      bw[g][kt].s = *(const s16x8_t*)(base + (long)kt*64*8);
  }

  float c[4], hacc[4] = {0,0,0,0}, cacc[4] = {0,0,0,0};
  {
    const long cb = (((long)p*16 + ct)*64 + l)*4;
    #pragma unroll
    for (int r=0;r<4;r++) c[r] = isFirst ? 0.f : cstate[cb + r];
  }
  float wreg[8];
  #pragma unroll
  for (int i=0;i<8;i++) wreg[i] = wtg[i];

  u16* hgrp = hxx + (long)p*2*4096;   // [slot][16][256]

  // prologue: publish own h_0 stripe with parity 0 (slot 0)
  #pragma unroll
  for (int r=0;r<4;r++){
    const int row = lg*4 + r, col = ct*16 + lr;
    u16 h0 = 0;
    if (!isFirst) h0 = hstate[dir*32768 + (slice*16 + row)*256 + col];
    __hip_atomic_store(hgrp + row*256 + col, (u16)(h0 & 0xFFFEu),
                       __ATOMIC_RELAXED, __HIP_MEMORY_SCOPE_AGENT);
  }

  // packed pre base for this (slice,ct,lane): 32B contiguous per step
  const u16* preT = pre + ((long)slice*16 + ct)*1024 + (long)l*16;
  s16x8_t pfA = *(const s16x8_t*)(preT);
  s16x8_t pfB = *(const s16x8_t*)(preT + 8);

  for (int t = 0; t < CT; t++){
    const u64 exp2 = ((t>>1)&1) ? MRK : 0ull;
    // lane reads row lr of h_t: 8 x 16B at stride 64B
    const u16* pb = hgrp + (t&1)*4096 + lr*256 + lg*8;

    // ---- issue the full h_t read EARLY (one batch, one round trip)
    Q8 z0, z1, z2, z3, z4, z5, z6, z7;
    asm volatile(
      "global_load_dwordx4 %0, %8, off sc0 sc1\n\t"
      "global_load_dwordx4 %1, %8, off offset:64 sc0 sc1\n\t"
      "global_load_dwordx4 %2, %8, off offset:128 sc0 sc1\n\t"
      "global_load_dwordx4 %3, %8, off offset:192 sc0 sc1\n\t"
      "global_load_dwordx4 %4, %8, off offset:256 sc0 sc1\n\t"
      "global_load_dwordx4 %5, %8, off offset:320 sc0 sc1\n\t"
      "global_load_dwordx4 %6, %8, off offset:384 sc0 sc1\n\t"
      "global_load_dwordx4 %7, %8, off offset:448 sc0 sc1"
      : "=&v"(z0.s), "=&v"(z1.s), "=&v"(z2.s), "=&v"(z3.s),
        "=&v"(z4.s), "=&v"(z5.s), "=&v"(z6.s), "=&v"(z7.s)
      : "v"(pb) : "memory");

    // acc init from packed pre (bf16 -> f32) — overlaps load latency
    f32x4_t acc[4];
    #pragma unroll
    for (int r=0; r<4; r++){
      acc[0][r] = bf2f((u16)pfA[r]);
      acc[1][r] = bf2f((u16)pfA[4+r]);
      acc[2][r] = bf2f((u16)pfB[r]);
      acc[3][r] = bf2f((u16)pfB[4+r]);
    }
    if (t + 1 < CT){
      const u16* pp = preT + (long)(t+1)*131072;
      pfA = *(const s16x8_t*)(pp);
      pfB = *(const s16x8_t*)(pp + 8);
    }

    // ---- wait + validate markers; retry = full re-batch
    asm volatile("s_waitcnt vmcnt(0)" ::: "memory");
    __builtin_amdgcn_sched_barrier(0);
    {
      int tries = 0;
      while (true){
        int ok = ((z0.q[0] & MRK) == exp2) & ((z0.q[1] & MRK) == exp2)
               & ((z1.q[0] & MRK) == exp2) & ((z1.q[1] & MRK) == exp2)
               & ((z2.q[0] & MRK) == exp2) & ((z2.q[1] & MRK) == exp2)
               & ((z3.q[0] & MRK) == exp2) & ((z3.q[1] & MRK) == exp2)
               & ((z4.q[0] & MRK) == exp2) & ((z4.q[1] & MRK) == exp2)
               & ((z5.q[0] & MRK) == exp2) & ((z5.q[1] & MRK) == exp2)
               & ((z6.q[0] & MRK) == exp2) & ((z6.q[1] & MRK) == exp2)
               & ((z7.q[0] & MRK) == exp2) & ((z7.q[1] & MRK) == exp2);
        if (__all(ok)) break;
        if (++tries > (1<<16)) break;    // fail loud (wrong result), not hang
        __builtin_amdgcn_s_sleep(1);
        asm volatile(
          "global_load_dwordx4 %0, %8, off sc0 sc1\n\t"
          "global_load_dwordx4 %1, %8, off offset:64 sc0 sc1\n\t"
          "global_load_dwordx4 %2, %8, off offset:128 sc0 sc1\n\t"
          "global_load_dwordx4 %3, %8, off offset:192 sc0 sc1\n\t"
          "global_load_dwordx4 %4, %8, off offset:256 sc0 sc1\n\t"
          "global_load_dwordx4 %5, %8, off offset:320 sc0 sc1\n\t"
          "global_load_dwordx4 %6, %8, off offset:384 sc0 sc1\n\t"
          "global_load_dwordx4 %7, %8, off offset:448 sc0 sc1\n\t"
          "s_waitcnt vmcnt(0)"
          : "=&v"(z0.s), "=&v"(z1.s), "=&v"(z2.s), "=&v"(z3.s),
            "=&v"(z4.s), "=&v"(z5.s), "=&v"(z6.s), "=&v"(z7.s)
          : "v"(pb) : "memory");
        __builtin_amdgcn_sched_barrier(0);
      }
    }

    // ---- full-K MFMAs: 8 kt x 4 gates (4 independent chains)
    {
      V8 a0, a1, a2, a3, a4, a5, a6, a7;
      a0.s = z0.s; a1.s = z1.s; a2.s = z2.s; a3.s = z3.s;
      a4.s = z4.s; a5.s = z5.s; a6.s = z6.s; a7.s = z7.s;
      #pragma unroll
      for (int g=0; g<4; g++){
        acc[g] = __builtin_amdgcn_mfma_f32_16x16x32_bf16(a0.b, bw[g][0].b, acc[g], 0,0,0);
        acc[g] = __builtin_amdgcn_mfma_f32_16x16x32_bf16(a1.b, bw[g][1].b, acc[g], 0,0,0);
        acc[g] = __builtin_amdgcn_mfma_f32_16x16x32_bf16(a2.b, bw[g][2].b, acc[g], 0,0,0);
        acc[g] = __builtin_amdgcn_mfma_f32_16x16x32_bf16(a3.b, bw[g][3].b, acc[g], 0,0,0);
        acc[g] = __builtin_amdgcn_mfma_f32_16x16x32_bf16(a4.b, bw[g][4].b, acc[g], 0,0,0);
        acc[g] = __builtin_amdgcn_mfma_f32_16x16x32_bf16(a5.b, bw[g][5].b, acc[g], 0,0,0);
        acc[g] = __builtin_amdgcn_mfma_f32_16x16x32_bf16(a6.b, bw[g][6].b, acc[g], 0,0,0);
        acc[g] = __builtin_amdgcn_mfma_f32_16x16x32_bf16(a7.b, bw[g][7].b, acc[g], 0,0,0);
      }
    }

    // ---- gates + state update (lane-local: 4 rows of one h-col)
    const float wtv = wreg[t & 7];
    const bool last = (t & 7) == 7;
    float hout[4];
    #pragma unroll
    for (int r=0;r<4;r++){
      float iv = sigmoidf_(acc[0][r]);
      float fv = sigmoidf_(acc[1][r]);
      float gv = tanhf_  (acc[2][r]);
      float ov = sigmoidf_(acc[3][r]);
      float cn = fv*c[r] + iv*gv;
      float hh = ov*tanhf_(cn);
      float ha = hacc[r] + wtv*hh;
      float ca = cacc[r] + wtv*cn;
      hout[r] = last ? ha : hh;
      c[r]    = last ? ca : cn;
      hacc[r] = last ? 0.f : ha;
      cacc[r] = last ? 0.f : ca;
    }

    // ---- publish h_{t+1}: 4 scattered marked 2B stores (fire-and-forget)
    u16 hb16[4];
    #pragma unroll
    for (int r=0;r<4;r++) hb16[r] = f2bf(hout[r]);
    if (t < CT - 1){
      const u16 pm1 = (u16)((((t+1)>>1)&1));
      u16* dst = hgrp + ((t+1)&1)*4096 + ct*16 + lr;
      #pragma unroll
      for (int r=0;r<4;r++){
        u16 v = (u16)((hb16[r] & 0xFFFEu) | pm1);
        __hip_atomic_store(dst + (lg*4+r)*256, v,
                           __ATOMIC_RELAXED, __HIP_MEMORY_SCOPE_AGENT);
      }
    }

    // ---- out write (clean values, fire-and-forget)
    {
      const long orow0 = (long)(outBase + t)*128 + slice*16;
      #pragma unroll
      for (int r=0;r<4;r++)
        out[(orow0 + lg*4 + r)*512 + dir*256 + ct*16 + lr] = hb16[r];
    }

    // ---- carry final h into hstate at the last step
    if (t == CT - 1){
      #pragma unroll
      for (int r=0;r<4;r++)
        hstate[dir*32768 + (slice*16 + lg*4 + r)*256 + ct*16 + lr] = hb16[r];
    }
  }

  // ---- c-state save
  {
    const long cb = (((long)p*16 + ct)*64 + l)*4;
    #pragma unroll
    for (int r=0;r<4;r++) cstate[cb + r] = c[r];
  }
}

// ---------------------------------------------------------------- output proj
__global__ __launch_bounds__(256) void kout(const u16* __restrict__ Ab,
    const u16* __restrict__ Wo, const float* __restrict__ bo,
    float* __restrict__ op, int chunkRow0)
{
  __shared__ u16 Ws[4096];
  __shared__ u16 Rs[32*520];
  const int tid = threadIdx.x;
  {
    int f = tid*8;
    *(s16x8_t*)&Ws[f] = *(const s16x8_t*)(Wo + f);
    *(s16x8_t*)&Ws[f+2048] = *(const s16x8_t*)(Wo + f + 2048);
  }
  const long row0 = (long)blockIdx.x*32;
  #pragma unroll
  for (int i=0;i<8;i++){
    int f = tid*8 + i*2048;
    int rr = f >> 9, cc = f & 511;
    *(s16x8_t*)&Rs[rr*520 + cc] = *(const s16x8_t*)(Ab + (row0+rr)*512 + cc);
  }
  __syncthreads();
  const int rr = tid >> 3, d = tid & 7;
  float s = bo[d];
  for (int k=0;k<512;k+=8){
    s16x8_t a = *(const s16x8_t*)&Rs[rr*520 + k];
    s16x8_t wv = *(const s16x8_t*)&Ws[d*512 + k];
    #pragma unroll
    for (int e=0;e<8;e++)
      s += bf2f((u16)a[e]) * bf2f((u16)wv[e]);
  }
  const long grow = chunkRow0 + row0 + rr;
  const int tt = (int)(grow >> 7), b2 = (int)(grow & 127);
  op[((long)b2*1024 + tt)*8 + d] = s;
}

// ---------------------------------------------------------------- log_softmax over t (dim=1)
__global__ __launch_bounds__(256) void lsm(float* __restrict__ io){
  const int b = blockIdx.x >> 3, d = blockIdx.x & 7;
  const int tid = threadIdx.x;
  __shared__ float red[4];
  float v[4];
  float mx = -3.4e38f;
  const long base = (long)b*1024*8 + d;
  #pragma unroll
  for (int i=0;i<4;i++){
    v[i] = io[base + (long)(tid + i*256)*8];
    mx = fmaxf(mx, v[i]);
  }
  #pragma unroll
  for (int off=32; off>=1; off>>=1) mx = fmaxf(mx, __shfl_down(mx, off, 64));
  if ((tid & 63) == 0) red[tid >> 6] = mx;
  __syncthreads();
  mx = fmaxf(fmaxf(red[0],red[1]), fmaxf(red[2],red[3]));
  __syncthreads();
  float s = 0.f;
  #pragma unroll
  for (int i=0;i<4;i++) s += __expf(v[i]-mx);
  #pragma unroll
  for (int off=32; off>=1; off>>=1) s += __shfl_down(s, off, 64);
  if ((tid & 63) == 0) red[tid >> 6] = s;
  __syncthreads();
  s = red[0]+red[1]+red[2]+red[3];
  float lse = mx + __logf(s);
  #pragma unroll
  for (int i=0;i<4;i++) io[base + (long)(tid + i*256)*8] = v[i] - lse;
}

// ---------------------------------------------------------------- launch
extern "C" void kernel_launch(void* const* d_in, const int* in_sizes, int n_in,
                              void* d_out, int out_size, void* d_ws, size_t ws_size,
                              hipStream_t stream){
  const float* x     = (const float*)d_in[0];
  const float* W_in  = (const float*)d_in[1];
  const float* b_in  = (const float*)d_in[2];
  const float* Wih1  = (const float*)d_in[3];
  const float* Whh1  = (const float*)d_in[4];
  const float* bih1  = (const float*)d_in[5];
  const float* bhh1  = (const float*)d_in[6];
  const float* Wih2  = (const float*)d_in[7];
  const float* Whh2  = (const float*)d_in[8];
  const float* bih2  = (const float*)d_in[9];
  const float* bhh2  = (const float*)d_in[10];
  const float* wt1   = (const float*)d_in[11];
  const float* wt2   = (const float*)d_in[12];
  const float* W_out = (const float*)d_in[13];
  const float* b_out = (const float*)d_in[14];

  auto rnd = [](size_t b){ return (b + 255) & ~(size_t)255; };

  const size_t ACT1B   = (size_t)TT*BB*512*2;       // 128 MB
  const size_t WIHB    = (size_t)GATES*INL*2;       // 1 MB
  const size_t WFRAGB  = (size_t)GATES*HIDN*2;      // 512 KB
  const size_t WINB    = (size_t)INL*DIN*2;
  const size_t WOUTB   = (size_t)DOUT*INL*2;
  const size_t HSTB    = (size_t)2*BB*HIDN*2;       // 128 KB
  const size_t CSTB    = (size_t)16*16*64*4*4;      // 256 KB
  const size_t HXB     = (size_t)16*2*4096*2;       // 256 KB (bf16, marked)

  const size_t fixedB = rnd(ACT1B) + 2*rnd(WIHB) + 2*rnd(WFRAGB) + rnd(WINB)
                      + rnd(WOUTB) + rnd(HSTB) + rnd(CSTB) + rnd(HXB);

  // pick largest chunk length whose budget fits ws_size (cands ≡ 0 mod 4:
  // marker parity ring stays safe across launches)
  int CT = 8;
  const int cands[8] = {1024,512,256,128,64,32,16,8};
  for (int ci = 0; ci < 8; ci++){
    int cand = cands[ci];
    size_t need = fixedB + rnd((size_t)cand*BB*512*2) + 2*rnd((size_t)cand*BB*GATES*2);
    if (need <= ws_size){ CT = cand; break; }
  }
  const int nc = TT / CT;

  char* ws = (char*)d_ws;
  size_t off = 0;
  auto alloc = [&](size_t bytes) -> void* {
    void* p = ws + off;
    off += rnd(bytes);
    return p;
  };

  u16*   act1    = (u16*)alloc(ACT1B);
  u16*   Wihb0   = (u16*)alloc(WIHB);
  u16*   Wihb1   = (u16*)alloc(WIHB);
  u16*   wfrag0  = (u16*)alloc(WFRAGB);
  u16*   wfrag1  = (u16*)alloc(WFRAGB);
  u16*   Winb    = (u16*)alloc(WINB);
  u16*   Woutb   = (u16*)alloc(WOUTB);
  u16*   hstate  = (u16*)alloc(HSTB);
  float* cstate  = (float*)alloc(CSTB);
  u16*   hxx     = (u16*)alloc(HXB);
  u16*   actchunk= (u16*)alloc((size_t)CT*BB*512*2);
  u16*   pre0    = (u16*)alloc((size_t)CT*BB*GATES*2);
  u16*   pre1    = (u16*)alloc((size_t)CT*BB*GATES*2);

  // invalidate exchange markers once per call: 0xFF -> every bf16 LSB = 1,
  // which never matches the parity-0 expectation of the first reads
  hipMemsetAsync(hxx, 0xFF, HXB, stream);

  // weight converts + packs
  cvt_f32_bf16<<<(GATES*INL/4 + 255)/256, 256, 0, stream>>>(Wih1, Wihb0, GATES*INL/4);
  cvt_f32_bf16<<<(GATES*INL/4 + 255)/256, 256, 0, stream>>>(Wih2, Wihb1, GATES*INL/4);
  cvt_f32_bf16<<<(INL*DIN/4 + 255)/256, 256, 0, stream>>>(W_in, Winb, INL*DIN/4);
  cvt_f32_bf16<<<(DOUT*INL/4 + 255)/256, 256, 0, stream>>>(W_out, Woutb, DOUT*INL/4);
  pack_whh<<<128, 256, 0, stream>>>(Whh1, wfrag0);
  pack_whh<<<128, 256, 0, stream>>>(Whh2, wfrag1);

  // ---- layer 1 (input proj recomputed per chunk from x)
  for (int c2 = 0; c2 < nc; c2++){
    gemm_tile<1,0><<<dim3(4, CT), 256, 0, stream>>>(x, Winb, actchunk,
        b_in, nullptr, DIN, 512, c2*CT, 1);
    gemm_tile<0,1><<<dim3(8, CT), 256, 0, stream>>>(actchunk, Wihb0, pre0,
        bih1, bhh1, INL, GATES, 0, 1);
    gemm_tile<1,0><<<dim3(4, CT), 256, 0, stream>>>(x, Winb, actchunk,
        b_in, nullptr, DIN, 512, 1023 - c2*CT, -1);
    gemm_tile<0,1><<<dim3(8, CT), 256, 0, stream>>>(actchunk, Wihb1, pre1,
        bih2, bhh2, INL, GATES, 0, 1);
    lstm_rec12<<<dim3(256), 64, 0, stream>>>(pre0, pre1, wfrag0, wfrag1,
        wt1, wt2, act1, c2*CT, CT, c2 == 0, hstate, cstate, hxx);
  }

  // ---- layer 2 (reads act1; output chunk -> fused small out-proj)
  for (int c2 = 0; c2 < nc; c2++){
    gemm_tile<0,1><<<dim3(8, CT), 256, 0, stream>>>(act1, Wihb0, pre0,
        bih1, bhh1, INL, GATES, c2*CT, 1);
    gemm_tile<0,1><<<dim3(8, CT), 256, 0, stream>>>(act1, Wihb1, pre1,
        bih2, bhh2, INL, GATES, 1023 - c2*CT, -1);
    lstm_rec12<<<dim3(256), 64, 0, stream>>>(pre0, pre1, wfrag0, wfrag1,
        wt1, wt2, actchunk, 0, CT, c2 == 0, hstate, cstate, hxx);
    kout<<<CT*4, 256, 0, stream>>>(actchunk, Woutb, b_out,
        (float*)d_out, c2*CT*128);
  }

  lsm<<<BB*DOUT, 256, 0, stream>>>((float*)d_out);
}